// Round 1
// 783.935 us; speedup vs baseline: 1.1016x; 1.1016x over previous
//
#include <hip/hip_runtime.h>
#include <hip/hip_bf16.h>
#include <cstdint>

#define SEQ  4096
#define DIM  768
#define NH   12
#define HDIM 64
#define NLAYER 2
#define CHK  256
#define WINR 256
#define NCLS 64
#define NCHK 16
#define FFD  3072
#define QSCALE 0.125f
#define LOG2E 1.44269504f
#define QSC2 (QSCALE * LOG2E)
#define SD ((size_t)SEQ * DIM)
#define PS_LD 72
#define TK 64

typedef __attribute__((__vector_size__(16))) float floatx4;
typedef __attribute__((ext_vector_type(8))) __bf16 bf16x8;
typedef __attribute__((ext_vector_type(4))) __bf16 bf16x4;

__device__ __forceinline__ void async16(const void* g, void* l) {
    __builtin_amdgcn_global_load_lds(
        (const __attribute__((address_space(1))) uint32_t*)g,
        (__attribute__((address_space(3))) uint32_t*)l, 16, 0, 0);
}

__device__ __forceinline__ float gelu_f(float x) {
    float x3 = x * x * x;
    return 0.5f * x * (1.0f + tanhf(0.7978845608028654f * (x + 0.044715f * x3)));
}

// ---------------- global-token rank init ----------------
__global__ __launch_bounds__(64) void set_rank_kernel(
    const int* __restrict__ clss, int* __restrict__ isglb, int* __restrict__ glb_rank)
{
    int t = threadIdx.x;
    int p = clss[t];
    isglb[p] = 1;
    glb_rank[p] = t;   // duplicates: either rank gives identical output rows
}

// ---------------- embedding + LN (wave-per-row, shuffle reduce) ----------------
__global__ __launch_bounds__(256) void embed_ln_kernel(
    const int* __restrict__ x, const int* __restrict__ segs,
    const float* __restrict__ word_emb, const float* __restrict__ pos_emb,
    const float* __restrict__ type_emb, const float* __restrict__ gs,
    const float* __restrict__ gb, float* __restrict__ h, __bf16* __restrict__ hb,
    int* __restrict__ isglb, int* __restrict__ grank)
{
    int wave = threadIdx.x >> 6, lane = threadIdx.x & 63;
    int s = blockIdx.x * 4 + wave;
    if (lane == 0) { isglb[s] = 0; grank[s] = -1; }
    int w = x[s], sg = segs[s];
    const float4* wp = (const float4*)(word_emb + (size_t)w * DIM);
    const float4* pp = (const float4*)(pos_emb + (size_t)s * DIM);
    const float4* tp = (const float4*)(type_emb + (size_t)sg * DIM);
    float4 v[3]; float lsum = 0.f;
    #pragma unroll
    for (int i = 0; i < 3; i++) {
        int d4 = lane + i * 64;
        float4 a = wp[d4], b = pp[d4], c = tp[d4];
        float4 r;
        r.x = a.x + b.x + c.x; r.y = a.y + b.y + c.y;
        r.z = a.z + b.z + c.z; r.w = a.w + b.w + c.w;
        v[i] = r; lsum += r.x + r.y + r.z + r.w;
    }
    #pragma unroll
    for (int st = 32; st > 0; st >>= 1) lsum += __shfl_xor(lsum, st);
    float mean = lsum * (1.0f / DIM);
    float lv = 0.f;
    #pragma unroll
    for (int i = 0; i < 3; i++) {
        float dx = v[i].x - mean, dy = v[i].y - mean, dz = v[i].z - mean, dw = v[i].w - mean;
        lv += dx * dx + dy * dy + dz * dz + dw * dw;
    }
    #pragma unroll
    for (int st = 32; st > 0; st >>= 1) lv += __shfl_xor(lv, st);
    float rstd = rsqrtf(lv * (1.0f / DIM) + 1e-5f);
    #pragma unroll
    for (int i = 0; i < 3; i++) {
        int d4 = lane + i * 64;
        float4 s4v = ((const float4*)gs)[d4], b4v = ((const float4*)gb)[d4];
        float4 o;
        o.x = (v[i].x - mean) * rstd * s4v.x + b4v.x;
        o.y = (v[i].y - mean) * rstd * s4v.y + b4v.y;
        o.z = (v[i].z - mean) * rstd * s4v.z + b4v.z;
        o.w = (v[i].w - mean) * rstd * s4v.w + b4v.w;
        ((float4*)(h + (size_t)s * DIM))[d4] = o;
        bf16x4 ob; ob[0] = (__bf16)o.x; ob[1] = (__bf16)o.y;
        ob[2] = (__bf16)o.z; ob[3] = (__bf16)o.w;
        *(bf16x4*)(hb + (size_t)s * DIM + (size_t)d4 * 4) = ob;
    }
}

// ---------------- residual add + LN (wave-per-row) ----------------
__global__ __launch_bounds__(256) void add_ln_kernel(
    const float* __restrict__ h, const float* __restrict__ r,
    const float* __restrict__ gs, const float* __restrict__ gb,
    float* __restrict__ hout, __bf16* __restrict__ hb)
{
    int wave = threadIdx.x >> 6, lane = threadIdx.x & 63;
    int s = blockIdx.x * 4 + wave;
    const float4* hp = (const float4*)(h + (size_t)s * DIM);
    const float4* rp = (const float4*)(r + (size_t)s * DIM);
    float4 v[3]; float lsum = 0.f;
    #pragma unroll
    for (int i = 0; i < 3; i++) {
        int d4 = lane + i * 64;
        float4 a = hp[d4], b = rp[d4];
        float4 q;
        q.x = a.x + b.x; q.y = a.y + b.y; q.z = a.z + b.z; q.w = a.w + b.w;
        v[i] = q; lsum += q.x + q.y + q.z + q.w;
    }
    #pragma unroll
    for (int st = 32; st > 0; st >>= 1) lsum += __shfl_xor(lsum, st);
    float mean = lsum * (1.0f / DIM);
    float lv = 0.f;
    #pragma unroll
    for (int i = 0; i < 3; i++) {
        float dx = v[i].x - mean, dy = v[i].y - mean, dz = v[i].z - mean, dw = v[i].w - mean;
        lv += dx * dx + dy * dy + dz * dz + dw * dw;
    }
    #pragma unroll
    for (int st = 32; st > 0; st >>= 1) lv += __shfl_xor(lv, st);
    float rstd = rsqrtf(lv * (1.0f / DIM) + 1e-5f);
    #pragma unroll
    for (int i = 0; i < 3; i++) {
        int d4 = lane + i * 64;
        float4 s4v = ((const float4*)gs)[d4], b4v = ((const float4*)gb)[d4];
        float4 o;
        o.x = (v[i].x - mean) * rstd * s4v.x + b4v.x;
        o.y = (v[i].y - mean) * rstd * s4v.y + b4v.y;
        o.z = (v[i].z - mean) * rstd * s4v.z + b4v.z;
        o.w = (v[i].w - mean) * rstd * s4v.w + b4v.w;
        ((float4*)(hout + (size_t)s * DIM))[d4] = o;
        bf16x4 ob; ob[0] = (__bf16)o.x; ob[1] = (__bf16)o.y;
        ob[2] = (__bf16)o.z; ob[3] = (__bf16)o.w;
        *(bf16x4*)(hb + (size_t)s * DIM + (size_t)d4 * 4) = ob;
    }
}

// ------- merged weight transpose-convert + bias concat (single dispatch) -------
// blocks [0,8064): 14 DxD transposes; [8064,12672): Wf1 (768x3072) x2;
// [12672,17280): Wf2 (3072x768) x2; [17280,17310): bias concat.
struct TArgs { const float* p14[14]; const float* f1[2]; const float* f2[2]; };
#define DD_ ((size_t)DIM * DIM)
__global__ __launch_bounds__(256) void tpose_setup_kernel(
    TArgs ta, __bf16* __restrict__ Wbf,
    const float* __restrict__ bq, const float* __restrict__ bk,
    const float* __restrict__ bv, const float* __restrict__ bkg,
    const float* __restrict__ bvg, float* __restrict__ bqkv)
{
    int b = blockIdx.x;
    if (b >= 17280) {
        int idx = (b - 17280) * 256 + threadIdx.x;   // 0..7679
        int l = idx / 3840, c = idx % 3840, j = c / 768, d = c % 768;
        const float* s = (j == 0) ? bq : (j == 1) ? bk : (j == 2) ? bv : (j == 3) ? bkg : bvg;
        bqkv[idx] = s[l * 768 + d];
        return;
    }
    const float* src; __bf16* dst; int K, N, bx, by;
    if (b < 8064) {
        int z = b / 576, rr = b % 576;
        src = ta.p14[z]; dst = Wbf + (size_t)z * DD_;
        K = 768; N = 768; bx = (rr % 24) * 32; by = (rr / 24) * 32;
    } else if (b < 12672) {
        int bb = b - 8064; int z = bb / 2304, rr = bb % 2304;
        src = ta.f1[z]; dst = Wbf + 14 * DD_ + (size_t)z * 4 * DD_;
        K = 768; N = 3072; bx = (rr % 96) * 32; by = (rr / 96) * 32;
    } else {
        int bb = b - 12672; int z = bb / 2304, rr = bb % 2304;
        src = ta.f2[z]; dst = Wbf + 22 * DD_ + (size_t)z * 4 * DD_;
        K = 3072; N = 768; bx = (rr % 24) * 32; by = (rr / 24) * 32;
    }
    __shared__ float tile[32][33];
    int tx = threadIdx.x & 31, ty = threadIdx.x >> 5;
    #pragma unroll
    for (int i = 0; i < 32; i += 8)
        tile[ty + i][tx] = src[(size_t)(by + ty + i) * N + bx + tx];
    __syncthreads();
    #pragma unroll
    for (int i = 0; i < 32; i += 8)
        dst[(size_t)(bx + ty + i) * K + by + tx] = (__bf16)tile[tx][ty + i];
}

// ================= generic templated MFMA GEMM (BK=64, XOR-swizzled LDS) =======
// LDS layout: linear dest for global_load_lds; source chunk pre-swizzled by
// (chunk ^ (row&7)); ds_read applies the same involution -> conflict-free-ish.
template<int TMv, int TNv>
__global__ __launch_bounds__(256) void mfma_gemm_t(
    const __bf16* __restrict__ A, const __bf16* __restrict__ Bt,
    const float* __restrict__ bias, float* __restrict__ Cf,
    __bf16* __restrict__ Cb, int M, int N, int K, float scale, int act)
{
    constexpr int AM = TMv / 32, AN = TNv / 32;
    constexpr int LA = TMv / 32, LB = TNv / 32;   // async16 per thread per step
    __shared__ __align__(16) __bf16 As[TMv * TK];
    __shared__ __align__(16) __bf16 Bs[TNv * TK];
    int t = threadIdx.x;
    int wave = t >> 6, lane = t & 63;
    int bm = blockIdx.x * TMv, bn = blockIdx.y * TNv;
    int wm = (wave & 1) * (TMv / 2), wn = (wave >> 1) * (TNv / 2);

    floatx4 acc[AM][AN];
    #pragma unroll
    for (int i = 0; i < AM; i++)
        #pragma unroll
        for (int j = 0; j < AN; j++) { floatx4 z = {0.f,0.f,0.f,0.f}; acc[i][j] = z; }

    const int mrow = lane & 15, kq = (lane >> 4) * 8;
    const int tr8 = lane >> 3, c8 = lane & 7;
    const int scol = (c8 ^ tr8) * 8;          // pre-swizzled source column
    const int swz = (lane & 7) << 3;          // read-side involution
    const __bf16* aBase = A  + (size_t)(bm + wave * 8 + tr8) * K + scol;
    const __bf16* bBase = Bt + (size_t)(bn + wave * 8 + tr8) * K + scol;

    for (int k0 = 0; k0 < K; k0 += TK) {
        __syncthreads();
        #pragma unroll
        for (int i = 0; i < LA; i++)
            async16(aBase + k0 + (size_t)i * 32 * K, &As[(size_t)(i * 256 + wave * 64) * 8]);
        #pragma unroll
        for (int i = 0; i < LB; i++)
            async16(bBase + k0 + (size_t)i * 32 * K, &Bs[(size_t)(i * 256 + wave * 64) * 8]);
        __builtin_amdgcn_s_waitcnt(0x0f70);
        __syncthreads();
        #pragma unroll
        for (int ks = 0; ks < 2; ks++) {
            const int e = (ks * 32 + kq) ^ swz;
            bf16x8 af[AM], bfr[AN];
            #pragma unroll
            for (int mt = 0; mt < AM; mt++)
                af[mt] = *(const bf16x8*)&As[(wm + mt * 16 + mrow) * TK + e];
            #pragma unroll
            for (int nt = 0; nt < AN; nt++)
                bfr[nt] = *(const bf16x8*)&Bs[(wn + nt * 16 + mrow) * TK + e];
            #pragma unroll
            for (int mt = 0; mt < AM; mt++)
                #pragma unroll
                for (int nt = 0; nt < AN; nt++)
                    acc[mt][nt] = __builtin_amdgcn_mfma_f32_16x16x32_bf16(
                        af[mt], bfr[nt], acc[mt][nt], 0, 0, 0);
        }
    }

    int col_l = lane & 15, row_l = (lane >> 4) * 4;
    #pragma unroll
    for (int nt = 0; nt < AN; nt++) {
        int col = bn + wn + nt * 16 + col_l;
        float bs = bias[col];
        #pragma unroll
        for (int mt = 0; mt < AM; mt++) {
            floatx4 v = acc[mt][nt];
            int row0 = bm + wm + mt * 16 + row_l;
            #pragma unroll
            for (int rr = 0; rr < 4; rr++) {
                float o = (v[rr] + bs) * scale;
                if (act) o = gelu_f(o);
                if (Cf) Cf[(size_t)(row0 + rr) * N + col] = o;
                if (Cb) Cb[(size_t)(row0 + rr) * N + col] = (__bf16)o;
            }
        }
    }
}

// ================= fused 5-way projection GEMM (q|k|v|kg|vg, N=3840) ===========
__global__ __launch_bounds__(256) void mfma_gemm_proj(
    const __bf16* __restrict__ A, const __bf16* __restrict__ Bt,
    const float* __restrict__ bias,
    __bf16* __restrict__ qb, __bf16* __restrict__ kb,
    __bf16* __restrict__ vb, __bf16* __restrict__ vtg,
    __bf16* __restrict__ kgb, __bf16* __restrict__ vgt, int K)
{
    __shared__ __align__(16) __bf16 As[128 * TK];
    __shared__ __align__(16) __bf16 Bs[128 * TK];
    int t = threadIdx.x;
    int wave = t >> 6, lane = t & 63;
    int bm = blockIdx.x * 128, bn = blockIdx.y * 128;
    int wm = (wave & 1) * 64, wn = (wave >> 1) * 64;

    floatx4 acc[4][4];
    #pragma unroll
    for (int i = 0; i < 4; i++)
        #pragma unroll
        for (int j = 0; j < 4; j++) { floatx4 z = {0.f,0.f,0.f,0.f}; acc[i][j] = z; }

    const int mrow = lane & 15, kq = (lane >> 4) * 8;
    const int tr8 = lane >> 3, c8 = lane & 7;
    const int scol = (c8 ^ tr8) * 8;
    const int swz = (lane & 7) << 3;
    const __bf16* aBase = A  + (size_t)(bm + wave * 8 + tr8) * K + scol;
    const __bf16* bBase = Bt + (size_t)(bn + wave * 8 + tr8) * K + scol;

    for (int k0 = 0; k0 < K; k0 += TK) {
        __syncthreads();
        #pragma unroll
        for (int i = 0; i < 4; i++) {
            async16(aBase + k0 + (size_t)i * 32 * K, &As[(size_t)(i * 256 + wave * 64) * 8]);
            async16(bBase + k0 + (size_t)i * 32 * K, &Bs[(size_t)(i * 256 + wave * 64) * 8]);
        }
        __builtin_amdgcn_s_waitcnt(0x0f70);
        __syncthreads();
        #pragma unroll
        for (int ks = 0; ks < 2; ks++) {
            const int e = (ks * 32 + kq) ^ swz;
            bf16x8 af[4], bfr[4];
            #pragma unroll
            for (int mt = 0; mt < 4; mt++)
                af[mt] = *(const bf16x8*)&As[(wm + mt * 16 + mrow) * TK + e];
            #pragma unroll
            for (int nt = 0; nt < 4; nt++)
                bfr[nt] = *(const bf16x8*)&Bs[(wn + nt * 16 + mrow) * TK + e];
            #pragma unroll
            for (int mt = 0; mt < 4; mt++)
                #pragma unroll
                for (int nt = 0; nt < 4; nt++)
                    acc[mt][nt] = __builtin_amdgcn_mfma_f32_16x16x32_bf16(
                        af[mt], bfr[nt], acc[mt][nt], 0, 0, 0);
        }
    }

    int col_l = lane & 15, row_l = (lane >> 4) * 4;
    int seg = bn / 768;                      // 0=q 1=k 2=v 3=kg 4=vg
    int colw_base = bn - seg * 768 + wn;
    float scl = (seg == 0) ? QSC2 : 1.0f;
    #pragma unroll
    for (int nt = 0; nt < 4; nt++) {
        int col = bn + wn + nt * 16 + col_l;
        int colw = colw_base + nt * 16 + col_l;
        float bs = bias[col];
        #pragma unroll
        for (int mt = 0; mt < 4; mt++) {
            floatx4 v = acc[mt][nt];
            int row0 = bm + wm + mt * 16 + row_l;
            __bf16 t4[4];
            #pragma unroll
            for (int rr = 0; rr < 4; rr++) t4[rr] = (__bf16)((v[rr] + bs) * scl);
            if (seg <= 2 || seg == 3) {
                __bf16* dst = (seg == 0) ? qb : (seg == 1) ? kb : (seg == 2) ? vb : kgb;
                #pragma unroll
                for (int rr = 0; rr < 4; rr++)
                    dst[(size_t)(row0 + rr) * 768 + colw] = t4[rr];
            }
            if (seg == 2)
                *(uint2*)&vtg[(size_t)colw * SEQ + row0] = *(uint2*)t4;
            if (seg == 4)
                *(uint2*)&vgt[(size_t)colw * SEQ + row0] = *(uint2*)t4;
        }
    }
}

// ================= qg projection with fused row-gather (BK=64) =================
__global__ __launch_bounds__(256) void qg_proj(
    const __bf16* __restrict__ hb, const __bf16* __restrict__ Bt,
    const int* __restrict__ clss, const float* __restrict__ bias,
    __bf16* __restrict__ out)
{
    __shared__ __align__(16) __bf16 As[64 * TK];
    __shared__ __align__(16) __bf16 Bs[128 * TK];
    int t = threadIdx.x;
    int wave = t >> 6, lane = t & 63;
    int bn = blockIdx.y * 128;
    int wm = (wave & 1) * 32, wn = (wave >> 1) * 64;

    const int mrow = lane & 15, kq = (lane >> 4) * 8;
    const int tr8 = lane >> 3, c8 = lane & 7;
    const int scol = (c8 ^ tr8) * 8;
    const int swz = (lane & 7) << 3;
    int arow0 = wave * 8 + tr8;               // 0..31
    int g0 = clss[arow0], g1 = clss[32 + arow0];
    const __bf16* a0 = hb + (size_t)g0 * DIM + scol;
    const __bf16* a1 = hb + (size_t)g1 * DIM + scol;
    const __bf16* bBase = Bt + (size_t)(bn + wave * 8 + tr8) * DIM + scol;

    floatx4 acc[2][4];
    #pragma unroll
    for (int i = 0; i < 2; i++)
        #pragma unroll
        for (int j = 0; j < 4; j++) { floatx4 z = {0.f,0.f,0.f,0.f}; acc[i][j] = z; }

    for (int k0 = 0; k0 < DIM; k0 += TK) {
        __syncthreads();
        async16(a0 + k0, &As[(size_t)(wave * 64) * 8]);
        async16(a1 + k0, &As[(size_t)(256 + wave * 64) * 8]);
        #pragma unroll
        for (int i = 0; i < 4; i++)
            async16(bBase + k0 + (size_t)i * 32 * DIM, &Bs[(size_t)(i * 256 + wave * 64) * 8]);
        __builtin_amdgcn_s_waitcnt(0x0f70);
        __syncthreads();
        #pragma unroll
        for (int ks = 0; ks < 2; ks++) {
            const int e = (ks * 32 + kq) ^ swz;
            bf16x8 af[2], bfr[4];
            #pragma unroll
            for (int mt = 0; mt < 2; mt++)
                af[mt] = *(const bf16x8*)&As[(wm + mt * 16 + mrow) * TK + e];
            #pragma unroll
            for (int nt = 0; nt < 4; nt++)
                bfr[nt] = *(const bf16x8*)&Bs[(wn + nt * 16 + mrow) * TK + e];
            #pragma unroll
            for (int mt = 0; mt < 2; mt++)
                #pragma unroll
                for (int nt = 0; nt < 4; nt++)
                    acc[mt][nt] = __builtin_amdgcn_mfma_f32_16x16x32_bf16(
                        af[mt], bfr[nt], acc[mt][nt], 0, 0, 0);
        }
    }
    int col_l = lane & 15, row_l = (lane >> 4) * 4;
    #pragma unroll
    for (int nt = 0; nt < 4; nt++) {
        int col = bn + wn + nt * 16 + col_l;
        float bs = bias[col];
        #pragma unroll
        for (int mt = 0; mt < 2; mt++) {
            floatx4 v = acc[mt][nt];
            int row0 = wm + mt * 16 + row_l;
            #pragma unroll
            for (int rr = 0; rr < 4; rr++)
                out[(size_t)(row0 + rr) * DIM + col] = (__bf16)((v[rr] + bs) * QSC2);
        }
    }
}

// ================= unified attention: band (z<4) + gq flash (z>=4) =============
__global__ __launch_bounds__(256) void attn_kernel(
    const __bf16* __restrict__ qb, const __bf16* __restrict__ kb,
    const __bf16* __restrict__ vb, const __bf16* __restrict__ vtg,
    const __bf16* __restrict__ qgbb, const __bf16* __restrict__ kgb,
    const __bf16* __restrict__ vgt,
    const int* __restrict__ clss, const int* __restrict__ mask_src,
    const int* __restrict__ is_glb,
    float* __restrict__ OpartB, float* __restrict__ mlpartB,
    float* __restrict__ OpartG, float* __restrict__ mlpartG)
{
    __shared__ __align__(16) __bf16 Kt[4096];
    __shared__ __align__(16) __bf16 Vt[4096];
    __shared__ __align__(16) __bf16 Ps[4][32 * PS_LD];
    __shared__ int kvalid[64];
    __shared__ int gpos[64];

    const int hh = blockIdx.y;
    const int t = threadIdx.x, wave = t >> 6, lane = t & 63;
    const int quad = lane >> 4, col_l = lane & 15, row_l = quad * 4;
    const int l3 = lane & 3, l2h = lane >> 2, l7 = lane & 7, l3h = lane >> 3;
    __bf16* PsW = Ps[wave];

    if (blockIdx.z >= 4) {
        // ---------- gq flash: split sp over 32, 4 waves x 16 queries ----------
        const int sp = blockIdx.x * 2 + (blockIdx.z - 4);
        bf16x8 aq[2];
        {
            const __bf16* qp = qgbb + (size_t)(wave * 16 + col_l) * DIM + hh * HDIM;
            aq[0] = *(const bf16x8*)(qp + quad * 8);
            aq[1] = *(const bf16x8*)(qp + 32 + quad * 8);
        }
        floatx4 oacc[4];
        #pragma unroll
        for (int i = 0; i < 4; i++) { floatx4 z = {0.f,0.f,0.f,0.f}; oacc[i] = z; }
        float m4[4], l4[4];
        #pragma unroll
        for (int r = 0; r < 4; r++) { m4[r] = -1e30f; l4[r] = 0.f; }

        for (int tt = 0; tt < 2; tt++) {
            int pos0 = sp * 128 + tt * 64;
            __syncthreads();
            if (t < 64) kvalid[t] = (mask_src[pos0 + t] > 0) ? 1 : 0;
            #pragma unroll
            for (int ii = 0; ii < 2; ii++) {
                int gid = wave * 2 + ii;
                int p = gid >> 2, kbase = (gid & 3) * 16;
                async16(kgb + (size_t)(pos0 + kbase + l2h) * DIM + hh * HDIM + p * 32 + l3 * 8,
                        &Kt[p * 2048 + kbase * 32]);
            }
            #pragma unroll
            for (int ii = 0; ii < 2; ii++) {
                int gid = wave * 2 + ii;
                int p = gid >> 2, dbase = (gid & 3) * 16;
                async16(vgt + (size_t)(hh * HDIM + dbase + l2h) * SEQ + pos0 + p * 32 + l3 * 8,
                        &Vt[p * 2048 + dbase * 32]);
            }
            __builtin_amdgcn_s_waitcnt(0x0f70);
            __syncthreads();

            floatx4 s[4];
            #pragma unroll
            for (int nt = 0; nt < 4; nt++) {
                bf16x8 b0 = *(const bf16x8*)&Kt[(nt * 16 + col_l) * 32 + quad * 8];
                bf16x8 b1 = *(const bf16x8*)&Kt[2048 + (nt * 16 + col_l) * 32 + quad * 8];
                floatx4 z = {0.f,0.f,0.f,0.f};
                z = __builtin_amdgcn_mfma_f32_16x16x32_bf16(aq[0], b0, z, 0,0,0);
                z = __builtin_amdgcn_mfma_f32_16x16x32_bf16(aq[1], b1, z, 0,0,0);
                s[nt] = z;
            }
            #pragma unroll
            for (int nt = 0; nt < 4; nt++) {
                int kvv = kvalid[nt * 16 + col_l];
                #pragma unroll
                for (int rr = 0; rr < 4; rr++)
                    if (!kvv) s[nt][rr] = -1e30f;
            }
            #pragma unroll
            for (int rr = 0; rr < 4; rr++) {
                float rm = fmaxf(fmaxf(s[0][rr], s[1][rr]), fmaxf(s[2][rr], s[3][rr]));
                rm = fmaxf(rm, __shfl_xor(rm, 1));
                rm = fmaxf(rm, __shfl_xor(rm, 2));
                rm = fmaxf(rm, __shfl_xor(rm, 4));
                rm = fmaxf(rm, __shfl_xor(rm, 8));
                float mo = m4[rr];
                float mn = fmaxf(mo, rm);
                float alpha = exp2f(mo - mn);
                float rsum = 0.f;
                #pragma unroll
                for (int nt = 0; nt < 4; nt++) {
                    float p = exp2f(s[nt][rr] - mn);
                    rsum += p;
                    PsW[(row_l + rr) * PS_LD + nt * 16 + col_l] = (__bf16)p;
                }
                rsum += __shfl_xor(rsum, 1);
                rsum += __shfl_xor(rsum, 2);
                rsum += __shfl_xor(rsum, 4);
                rsum += __shfl_xor(rsum, 8);
                l4[rr] = l4[rr] * alpha + rsum;
                m4[rr] = mn;
                #pragma unroll
                for (int nt = 0; nt < 4; nt++) oacc[nt][rr] *= alpha;
            }
            bf16x8 ap0 = *(const bf16x8*)&PsW[col_l * PS_LD + quad * 8];
            bf16x8 ap1 = *(const bf16x8*)&PsW[col_l * PS_LD + 32 + quad * 8];
            #pragma unroll
            for (int nt = 0; nt < 4; nt++) {
                bf16x8 b0 = *(const bf16x8*)&Vt[(nt * 16 + col_l) * 32 + quad * 8];
                bf16x8 b1 = *(const bf16x8*)&Vt[2048 + (nt * 16 + col_l) * 32 + quad * 8];
                oacc[nt] = __builtin_amdgcn_mfma_f32_16x16x32_bf16(ap0, b0, oacc[nt], 0,0,0);
                oacc[nt] = __builtin_amdgcn_mfma_f32_16x16x32_bf16(ap1, b1, oacc[nt], 0,0,0);
            }
        }
        size_t base = (size_t)(hh * 32 + sp) * 64;
        #pragma unroll
        for (int nt = 0; nt < 4; nt++)
            #pragma unroll
            for (int rr = 0; rr < 4; rr++)
                OpartG[(base + wave * 16 + row_l + rr) * 64 + nt * 16 + col_l] = oacc[nt][rr];
        if (col_l == 0) {
            #pragma unroll
            for (int rr = 0; rr < 4; rr++) {
                mlpartG[(base + wave * 16 + row_l + rr) * 2]     = m4[rr];
                mlpartG[(base + wave * 16 + row_l + rr) * 2 + 1] = l4[rr];
            }
        }
        return;
    }

    // ---------- band + global-key flash (split-K over 2) ----------
    const int n = blockIdx.x, zi = blockIdx.z;
    const int qh = zi >> 1, ks = zi & 1;
    const int qw = qh * 128 + wave * 32;

    if (t < 64) gpos[t] = clss[t];

    bf16x8 aq[2][2];
    #pragma unroll
    for (int mt = 0; mt < 2; mt++) {
        const __bf16* qp = qb + (size_t)(n * CHK + qw + mt * 16 + col_l) * DIM + hh * HDIM;
        aq[mt][0] = *(const bf16x8*)(qp + quad * 8);
        aq[mt][1] = *(const bf16x8*)(qp + 32 + quad * 8);
    }

    floatx4 oacc[2][4];
    #pragma unroll
    for (int i = 0; i < 2; i++)
        #pragma unroll
        for (int j = 0; j < 4; j++) { floatx4 z = {0.f,0.f,0.f,0.f}; oacc[i][j] = z; }
    float mrw[8], lrw[8];
    #pragma unroll
    for (int r = 0; r < 8; r++) { mrw[r] = -1e30f; lrw[r] = 0.f; }

    const int ntiles = ks ? 5 : 6;

    for (int tt = 0; tt < ntiles; tt++) {
        __syncthreads();
        int jbase = -1;
        int isglob = (ks == 0 && tt == 0);
        if (isglob) {
            if (t < 64) kvalid[t] = (mask_src[gpos[t]] > 0) ? 1 : 0;
            #pragma unroll
            for (int g = 0; g < 2; g++) {
                int gid = wave * 2 + g;
                int p = gid >> 2, kbase = (gid & 3) * 16;
                int pos = gpos[kbase + l2h];
                async16(kb + (size_t)pos * DIM + hh * HDIM + p * 32 + l3 * 8,
                        &Kt[p * 2048 + kbase * 32]);
            }
            __bf16* Vrow = &Ps[0][0];
            #pragma unroll
            for (int g = 0; g < 2; g++) {
                int cg = wave * 2 + g;
                int pos = gpos[cg * 8 + l3h];
                async16(vb + (size_t)pos * DIM + hh * HDIM + l7 * 8,
                        &Vrow[cg * 64 * 8]);
            }
        } else {
            int jt = ks ? (qh * 2 + 5 + tt) : (qh * 2 + tt - 1);
            jbase = jt * 64;
            if (t < 64) {
                int pos = n * CHK + jbase + t - CHK;
                kvalid[t] = (pos >= 0 && pos < SEQ && mask_src[pos] > 0
                             && is_glb[pos] == 0) ? 1 : 0;
            }
            int s0 = n * CHK + jbase - CHK;
            #pragma unroll
            for (int g = 0; g < 2; g++) {
                int gid = wave * 2 + g;
                int p = gid >> 2, kbase = (gid & 3) * 16;
                int pos = s0 + kbase + l2h; pos = min(max(pos, 0), SEQ - 1);
                async16(kb + (size_t)pos * DIM + hh * HDIM + p * 32 + l3 * 8,
                        &Kt[p * 2048 + kbase * 32]);
            }
            #pragma unroll
            for (int g = 0; g < 2; g++) {
                int gid = wave * 2 + g;
                int p = gid >> 2, dbase = (gid & 3) * 16;
                int d = dbase + l2h;
                int s = s0 + p * 32 + l3 * 8; s = min(max(s, 0), SEQ - 8);
                async16(vtg + (size_t)(hh * HDIM + d) * SEQ + s,
                        &Vt[p * 2048 + dbase * 32]);
            }
        }
        __builtin_amdgcn_s_waitcnt(0x0f70);
        __syncthreads();
        if (isglob) {
            const __bf16* Vrow = &Ps[0][0];
            for (int idx = t; idx < 4096; idx += 256) {
                int key = idx >> 6, d = idx & 63;
                Vt[(key >> 5) * 2048 + d * 32 + (key & 31)] = Vrow[idx];
            }
            __syncthreads();
        } else {
            if (jbase + 63 < qw || jbase > qw + 543) continue;
        }

        bf16x8 bkf[4][2];
        #pragma unroll
        for (int nt = 0; nt < 4; nt++) {
            bkf[nt][0] = *(const bf16x8*)&Kt[(nt * 16 + col_l) * 32 + quad * 8];
            bkf[nt][1] = *(const bf16x8*)&Kt[2048 + (nt * 16 + col_l) * 32 + quad * 8];
        }
        int kv[4];
        #pragma unroll
        for (int nt = 0; nt < 4; nt++) kv[nt] = kvalid[nt * 16 + col_l];

        #pragma unroll
        for (int mt = 0; mt < 2; mt++) {
            floatx4 s[4];
            #pragma unroll
            for (int nt = 0; nt < 4; nt++) {
                floatx4 z = {0.f,0.f,0.f,0.f};
                z = __builtin_amdgcn_mfma_f32_16x16x32_bf16(aq[mt][0], bkf[nt][0], z, 0,0,0);
                z = __builtin_amdgcn_mfma_f32_16x16x32_bf16(aq[mt][1], bkf[nt][1], z, 0,0,0);
                s[nt] = z;
            }
            #pragma unroll
            for (int nt = 0; nt < 4; nt++)
                #pragma unroll
                for (int rr = 0; rr < 4; rr++) {
                    int ok = kv[nt];
                    if (!isglob) {
                        int i = qw + mt * 16 + row_l + rr;
                        int rel = jbase + nt * 16 + col_l - i;
                        ok = ok && (rel >= 0) && (rel <= 2 * WINR);
                    }
                    if (!ok) s[nt][rr] = -1e30f;
                }
            #pragma unroll
            for (int rr = 0; rr < 4; rr++) {
                float rm = fmaxf(fmaxf(s[0][rr], s[1][rr]), fmaxf(s[2][rr], s[3][rr]));
                rm = fmaxf(rm, __shfl_xor(rm, 1));
                rm = fmaxf(rm, __shfl_xor(rm, 2));
                rm = fmaxf(rm, __shfl_xor(rm, 4));
                rm = fmaxf(rm, __shfl_xor(rm, 8));
                int ri = mt * 4 + rr;
                float mo = mrw[ri];
                float mn = fmaxf(mo, rm);
                float alpha = exp2f(mo - mn);
                float rsum = 0.f;
                #pragma unroll
                for (int nt = 0; nt < 4; nt++) {
                    float p = exp2f(s[nt][rr] - mn);
                    rsum += p;
                    PsW[(mt * 16 + row_l + rr) * PS_LD + nt * 16 + col_l] = (__bf16)p;
                }
                rsum += __shfl_xor(rsum, 1);
                rsum += __shfl_xor(rsum, 2);
                rsum += __shfl_xor(rsum, 4);
                rsum += __shfl_xor(rsum, 8);
                lrw[ri] = lrw[ri] * alpha + rsum;
                mrw[ri] = mn;
                #pragma unroll
                for (int nt = 0; nt < 4; nt++) oacc[mt][nt][rr] *= alpha;
            }
        }
        bf16x8 bvf[4][2], ap[2][2];
        #pragma unroll
        for (int nt = 0; nt < 4; nt++) {
            bvf[nt][0] = *(const bf16x8*)&Vt[(nt * 16 + col_l) * 32 + quad * 8];
            bvf[nt][1] = *(const bf16x8*)&Vt[2048 + (nt * 16 + col_l) * 32 + quad * 8];
        }
        #pragma unroll
        for (int mt = 0; mt < 2; mt++) {
            ap[mt][0] = *(const bf16x8*)&PsW[(mt * 16 + col_l) * PS_LD + quad * 8];
            ap[mt][1] = *(const bf16x8*)&PsW[(mt * 16 + col_l) * PS_LD + 32 + quad * 8];
        }
        #pragma unroll
        for (int mt = 0; mt < 2; mt++)
            #pragma unroll
            for (int nt = 0; nt < 4; nt++) {
                oacc[mt][nt] = __builtin_amdgcn_mfma_f32_16x16x32_bf16(
                    ap[mt][0], bvf[nt][0], oacc[mt][nt], 0,0,0);
                oacc[mt][nt] = __builtin_amdgcn_mfma_f32_16x16x32_bf16(
                    ap[mt][1], bvf[nt][1], oacc[mt][nt], 0,0,0);
            }
    }

    #pragma unroll
    for (int mt = 0; mt < 2; mt++) {
        #pragma unroll
        for (int rr = 0; rr < 4; rr++) {
            int srow = n * CHK + qw + mt * 16 + row_l + rr;
            size_t rbase = ((size_t)ks * SEQ + srow) * NH + hh;
            #pragma unroll
            for (int nt = 0; nt < 4; nt++)
                OpartB[rbase * 64 + nt * 16 + col_l] = oacc[mt][nt][rr];
            if (col_l == 0) {
                mlpartB[rbase * 2]     = mrw[mt * 4 + rr];
                mlpartB[rbase * 2 + 1] = lrw[mt * 4 + rr];
            }
        }
    }
}

// ---------------- finalize: band 2-way merge / gq 32-way merge + scatter -------
__global__ __launch_bounds__(256) void attn_finalize(
    const float* __restrict__ OpartB, const float* __restrict__ mlpartB,
    const float* __restrict__ OpartG, const float* __restrict__ mlpartG,
    const int* __restrict__ glb_rank, __bf16* __restrict__ outb)
{
    int g = threadIdx.x >> 6, d = threadIdx.x & 63;
    int s = blockIdx.x * 4 + g, hh = blockIdx.y;
    int r = glb_rank[s];
    float o;
    if (r >= 0) {
        float M = -1e30f;
        for (int sp = 0; sp < 32; sp++)
            M = fmaxf(M, mlpartG[(((size_t)hh * 32 + sp) * 64 + r) * 2]);
        float L = 0.f, acc = 0.f;
        for (int sp = 0; sp < 32; sp++) {
            size_t b = ((size_t)hh * 32 + sp) * 64 + r;
            float w = exp2f(mlpartG[b * 2] - M);
            L += mlpartG[b * 2 + 1] * w;
            acc += w * OpartG[b * 64 + d];
        }
        o = acc / L;
    } else {
        size_t r0 = ((size_t)s) * NH + hh;
        size_t r1 = ((size_t)SEQ + s) * NH + hh;
        float m0 = mlpartB[r0 * 2], l0 = mlpartB[r0 * 2 + 1];
        float m1 = mlpartB[r1 * 2], l1 = mlpartB[r1 * 2 + 1];
        float M = fmaxf(m0, m1);
        float w0 = exp2f(m0 - M), w1 = exp2f(m1 - M);
        o = (OpartB[r0 * 64 + d] * w0 + OpartB[r1 * 64 + d] * w1) / (l0 * w0 + l1 * w1);
    }
    outb[(size_t)s * DIM + hh * HDIM + d] = (__bf16)o;
}

// ---------------- host launcher ----------------
extern "C" void kernel_launch(void* const* d_in, const int* in_sizes, int n_in,
                              void* d_out, int out_size, void* d_ws, size_t ws_size,
                              hipStream_t stream)
{
    const int* x        = (const int*)d_in[0];
    const int* mask_src = (const int*)d_in[1];
    const int* clss     = (const int*)d_in[2];
    const int* segs     = (const int*)d_in[3];
    const float* word_emb = (const float*)d_in[4];
    const float* pos_emb  = (const float*)d_in[5];
    const float* type_emb = (const float*)d_in[6];
    const float* ln_e_s   = (const float*)d_in[7];
    const float* ln_e_b   = (const float*)d_in[8];
    const float* Wq  = (const float*)d_in[9];
    const float* bq  = (const float*)d_in[10];
    const float* Wk  = (const float*)d_in[11];
    const float* bk  = (const float*)d_in[12];
    const float* Wv  = (const float*)d_in[13];
    const float* bv  = (const float*)d_in[14];
    const float* Wqg = (const float*)d_in[15];
    const float* bqg = (const float*)d_in[16];
    const float* Wkg = (const float*)d_in[17];
    const float* bkg = (const float*)d_in[18];
    const float* Wvg = (const float*)d_in[19];
    const float* bvg = (const float*)d_in[20];
    const float* Wo  = (const float*)d_in[21];
    const float* bo  = (const float*)d_in[22];
    const float* ln1_s = (const float*)d_in[23];
    const float* ln1_b = (const float*)d_in[24];
    const float* Wf1 = (const float*)d_in[25];
    const float* bf1 = (const float*)d_in[26];
    const float* Wf2 = (const float*)d_in[27];
    const float* bf2 = (const float*)d_in[28];
    const float* ln2_s = (const float*)d_in[29];
    const float* ln2_b = (const float*)d_in[30];

    const size_t DD = (size_t)DIM * DIM;
    float* ws = (float*)d_ws;
    float*  h    = ws;
    float*  s4   = ws + SD;
    __bf16* hb   = (__bf16*)(ws + 2 * SD);
    __bf16* b6b  = (__bf16*)(ws + 2 * SD) + SD;
    __bf16* qb   = (__bf16*)(ws + 3 * SD);
    __bf16* kb   = (__bf16*)(ws + 3 * SD) + SD;
    __bf16* vb   = (__bf16*)(ws + 4 * SD);
    __bf16* vtg  = (__bf16*)(ws + 4 * SD) + SD;
    __bf16* kgb  = (__bf16*)(ws + 5 * SD);
    __bf16* vgt  = (__bf16*)(ws + 5 * SD) + SD;
    __bf16* gelu_b = qb;
    float* extra = ws + 6 * SD;
    __bf16* Wbf   = (__bf16*)extra;                     // 30*DD bf16
    float* after_w = extra + 15 * DD;
    float* bqkv   = after_w;                            // 2*3840
    float* OpartG = bqkv + 7680;                        // 12*32*64*64 = 1,572,864
    float* mlpartG= OpartG + 1572864;                   // 49,152
    float* OpartB = mlpartG + 49152;                    // 2*4096*12*64 = 6,291,456
    float* mlpartB= OpartB + 6291456;                   // 196,608
    __bf16* qgbb  = (__bf16*)(mlpartB + 196608);        // 64*768 bf16
    int*   isglb  = (int*)(qgbb + (size_t)NCLS * DIM);  // SEQ
    int*   grank  = isglb + SEQ;                        // SEQ

    embed_ln_kernel<<<SEQ / 4, 256, 0, stream>>>(x, segs, word_emb, pos_emb, type_emb,
                                                 ln_e_s, ln_e_b, h, hb, isglb, grank);
    set_rank_kernel<<<1, 64, 0, stream>>>(clss, isglb, grank);
    {
        TArgs ta{};
        ta.p14[0] = Wq;        ta.p14[1] = Wk;        ta.p14[2] = Wv;
        ta.p14[3] = Wkg;       ta.p14[4] = Wvg;
        ta.p14[5] = Wq + DD;   ta.p14[6] = Wk + DD;   ta.p14[7] = Wv + DD;
        ta.p14[8] = Wkg + DD;  ta.p14[9] = Wvg + DD;
        ta.p14[10] = Wo;       ta.p14[11] = Wo + DD;
        ta.p14[12] = Wqg;      ta.p14[13] = Wqg + DD;
        ta.f1[0] = Wf1; ta.f1[1] = Wf1 + (size_t)DIM * FFD;
        ta.f2[0] = Wf2; ta.f2[1] = Wf2 + (size_t)FFD * DIM;
        tpose_setup_kernel<<<17310, 256, 0, stream>>>(ta, Wbf, bq, bk, bv, bkg, bvg, bqkv);
    }

    for (int l = 0; l < NLAYER; l++) {
        const float* bqg_l = bqg + (size_t)l * DIM;
        const float* bo_l  = bo  + (size_t)l * DIM;
        const float* bf1_l = bf1 + (size_t)l * FFD;
        const float* bf2_l = bf2 + (size_t)l * DIM;

        // qg projection (gather fused) -- independent of proj, needed by attn z>=4
        qg_proj<<<dim3(1, 6), 256, 0, stream>>>(
            hb, Wbf + 12 * DD + (size_t)l * DD, clss, bqg_l, qgbb);
        // fused 5-way projection
        mfma_gemm_proj<<<dim3(SEQ / 128, 3840 / 128), 256, 0, stream>>>(
            hb, Wbf + (size_t)l * 5 * DD, bqkv + l * 3840,
            qb, kb, vb, vtg, kgb, vgt, DIM);
        // unified band + gq attention
        attn_kernel<<<dim3(NCHK, NH, 6), 256, 0, stream>>>(
            qb, kb, vb, vtg, qgbb, kgb, vgt, clss, mask_src, isglb,
            OpartB, mlpartB, OpartG, mlpartG);
        attn_finalize<<<dim3(SEQ / 4, NH), 256, 0, stream>>>(
            OpartB, mlpartB, OpartG, mlpartG, grank, b6b);
        // output projection + LN1
        mfma_gemm_t<128, 64><<<dim3(SEQ / 128, DIM / 64), 256, 0, stream>>>(
            b6b, Wbf + 10 * DD + (size_t)l * DD, bo_l, s4, nullptr,
            SEQ, DIM, DIM, 1.0f, 0);
        add_ln_kernel<<<SEQ / 4, 256, 0, stream>>>(h, s4, ln1_s + (size_t)l * DIM,
                                                   ln1_b + (size_t)l * DIM, h, hb);
        // FFN
        mfma_gemm_t<128, 128><<<dim3(SEQ / 128, FFD / 128), 256, 0, stream>>>(
            hb, Wbf + 14 * DD + (size_t)l * 4 * DD, bf1_l, nullptr, gelu_b,
            SEQ, FFD, DIM, 1.0f, 1);
        mfma_gemm_t<128, 64><<<dim3(SEQ / 128, DIM / 64), 256, 0, stream>>>(
            gelu_b, Wbf + 22 * DD + (size_t)l * 4 * DD, bf2_l, s4, nullptr,
            SEQ, DIM, FFD, 1.0f, 0);
        // last LN writes the f32 output directly (removes the final D2D copy)
        add_ln_kernel<<<SEQ / 4, 256, 0, stream>>>(h, s4, ln2_s + (size_t)l * DIM,
                                                   ln2_b + (size_t)l * DIM,
                                                   (l == NLAYER - 1) ? (float*)d_out : h, hb);
    }
}

// Round 2
// 721.789 us; speedup vs baseline: 1.1965x; 1.0861x over previous
//
#include <hip/hip_runtime.h>
#include <hip/hip_bf16.h>
#include <cstdint>

#define SEQ  4096
#define DIM  768
#define NH   12
#define HDIM 64
#define NLAYER 2
#define CHK  256
#define WINR 256
#define NCLS 64
#define NCHK 16
#define FFD  3072
#define QSCALE 0.125f
#define LOG2E 1.44269504f
#define QSC2 (QSCALE * LOG2E)
#define SD ((size_t)SEQ * DIM)
#define PS_LD 72
#define TK 64

typedef __attribute__((__vector_size__(16))) float floatx4;
typedef __attribute__((ext_vector_type(8))) __bf16 bf16x8;
typedef __attribute__((ext_vector_type(4))) __bf16 bf16x4;

__device__ __forceinline__ void async16(const void* g, void* l) {
    __builtin_amdgcn_global_load_lds(
        (const __attribute__((address_space(1))) uint32_t*)g,
        (__attribute__((address_space(3))) uint32_t*)l, 16, 0, 0);
}

__device__ __forceinline__ float gelu_f(float x) {
    float x3 = x * x * x;
    return 0.5f * x * (1.0f + tanhf(0.7978845608028654f * (x + 0.044715f * x3)));
}

// ---------------- global-token flag init ----------------
__global__ __launch_bounds__(64) void set_rank_kernel(
    const int* __restrict__ clss, int* __restrict__ isglb)
{
    isglb[clss[threadIdx.x]] = 1;
}

// ---------------- embedding + LN (wave-per-row, shuffle reduce) ----------------
__global__ __launch_bounds__(256) void embed_ln_kernel(
    const int* __restrict__ x, const int* __restrict__ segs,
    const float* __restrict__ word_emb, const float* __restrict__ pos_emb,
    const float* __restrict__ type_emb, const float* __restrict__ gs,
    const float* __restrict__ gb, float* __restrict__ h, __bf16* __restrict__ hb,
    int* __restrict__ isglb)
{
    int wave = threadIdx.x >> 6, lane = threadIdx.x & 63;
    int s = blockIdx.x * 4 + wave;
    if (lane == 0) isglb[s] = 0;
    int w = x[s], sg = segs[s];
    const float4* wp = (const float4*)(word_emb + (size_t)w * DIM);
    const float4* pp = (const float4*)(pos_emb + (size_t)s * DIM);
    const float4* tp = (const float4*)(type_emb + (size_t)sg * DIM);
    float4 v[3]; float lsum = 0.f;
    #pragma unroll
    for (int i = 0; i < 3; i++) {
        int d4 = lane + i * 64;
        float4 a = wp[d4], b = pp[d4], c = tp[d4];
        float4 r;
        r.x = a.x + b.x + c.x; r.y = a.y + b.y + c.y;
        r.z = a.z + b.z + c.z; r.w = a.w + b.w + c.w;
        v[i] = r; lsum += r.x + r.y + r.z + r.w;
    }
    #pragma unroll
    for (int st = 32; st > 0; st >>= 1) lsum += __shfl_xor(lsum, st);
    float mean = lsum * (1.0f / DIM);
    float lv = 0.f;
    #pragma unroll
    for (int i = 0; i < 3; i++) {
        float dx = v[i].x - mean, dy = v[i].y - mean, dz = v[i].z - mean, dw = v[i].w - mean;
        lv += dx * dx + dy * dy + dz * dz + dw * dw;
    }
    #pragma unroll
    for (int st = 32; st > 0; st >>= 1) lv += __shfl_xor(lv, st);
    float rstd = rsqrtf(lv * (1.0f / DIM) + 1e-5f);
    #pragma unroll
    for (int i = 0; i < 3; i++) {
        int d4 = lane + i * 64;
        float4 s4v = ((const float4*)gs)[d4], b4v = ((const float4*)gb)[d4];
        float4 o;
        o.x = (v[i].x - mean) * rstd * s4v.x + b4v.x;
        o.y = (v[i].y - mean) * rstd * s4v.y + b4v.y;
        o.z = (v[i].z - mean) * rstd * s4v.z + b4v.z;
        o.w = (v[i].w - mean) * rstd * s4v.w + b4v.w;
        ((float4*)(h + (size_t)s * DIM))[d4] = o;
        bf16x4 ob; ob[0] = (__bf16)o.x; ob[1] = (__bf16)o.y;
        ob[2] = (__bf16)o.z; ob[3] = (__bf16)o.w;
        *(bf16x4*)(hb + (size_t)s * DIM + (size_t)d4 * 4) = ob;
    }
}

// ---------------- residual(2) add + LN (wave-per-row) ----------------
__global__ __launch_bounds__(256) void add_ln_kernel(
    const float* __restrict__ h, const float* __restrict__ r,
    const float* __restrict__ r2,
    const float* __restrict__ gs, const float* __restrict__ gb,
    float* __restrict__ hout, __bf16* __restrict__ hb)
{
    int wave = threadIdx.x >> 6, lane = threadIdx.x & 63;
    int s = blockIdx.x * 4 + wave;
    const float4* hp = (const float4*)(h + (size_t)s * DIM);
    const float4* rp = (const float4*)(r + (size_t)s * DIM);
    const float4* rp2 = (const float4*)(r2 + (size_t)s * DIM);
    float4 v[3]; float lsum = 0.f;
    #pragma unroll
    for (int i = 0; i < 3; i++) {
        int d4 = lane + i * 64;
        float4 a = hp[d4], b = rp[d4], c = rp2[d4];
        float4 q;
        q.x = a.x + b.x + c.x; q.y = a.y + b.y + c.y;
        q.z = a.z + b.z + c.z; q.w = a.w + b.w + c.w;
        v[i] = q; lsum += q.x + q.y + q.z + q.w;
    }
    #pragma unroll
    for (int st = 32; st > 0; st >>= 1) lsum += __shfl_xor(lsum, st);
    float mean = lsum * (1.0f / DIM);
    float lv = 0.f;
    #pragma unroll
    for (int i = 0; i < 3; i++) {
        float dx = v[i].x - mean, dy = v[i].y - mean, dz = v[i].z - mean, dw = v[i].w - mean;
        lv += dx * dx + dy * dy + dz * dz + dw * dw;
    }
    #pragma unroll
    for (int st = 32; st > 0; st >>= 1) lv += __shfl_xor(lv, st);
    float rstd = rsqrtf(lv * (1.0f / DIM) + 1e-5f);
    #pragma unroll
    for (int i = 0; i < 3; i++) {
        int d4 = lane + i * 64;
        float4 s4v = ((const float4*)gs)[d4], b4v = ((const float4*)gb)[d4];
        float4 o;
        o.x = (v[i].x - mean) * rstd * s4v.x + b4v.x;
        o.y = (v[i].y - mean) * rstd * s4v.y + b4v.y;
        o.z = (v[i].z - mean) * rstd * s4v.z + b4v.z;
        o.w = (v[i].w - mean) * rstd * s4v.w + b4v.w;
        ((float4*)(hout + (size_t)s * DIM))[d4] = o;
        bf16x4 ob; ob[0] = (__bf16)o.x; ob[1] = (__bf16)o.y;
        ob[2] = (__bf16)o.z; ob[3] = (__bf16)o.w;
        *(bf16x4*)(hb + (size_t)s * DIM + (size_t)d4 * 4) = ob;
    }
}

// ------- merged weight transpose-convert + bias concat (single dispatch) -------
struct TArgs { const float* p14[14]; const float* f1[2]; const float* f2[2]; };
#define DD_ ((size_t)DIM * DIM)
__global__ __launch_bounds__(256) void tpose_setup_kernel(
    TArgs ta, __bf16* __restrict__ Wbf,
    const float* __restrict__ bq, const float* __restrict__ bk,
    const float* __restrict__ bv, const float* __restrict__ bkg,
    const float* __restrict__ bvg, float* __restrict__ bqkv)
{
    int b = blockIdx.x;
    if (b >= 17280) {
        int idx = (b - 17280) * 256 + threadIdx.x;   // 0..7679
        int l = idx / 3840, c = idx % 3840, j = c / 768, d = c % 768;
        const float* s = (j == 0) ? bq : (j == 1) ? bk : (j == 2) ? bv : (j == 3) ? bkg : bvg;
        bqkv[idx] = s[l * 768 + d];
        return;
    }
    const float* src; __bf16* dst; int K, N, bx, by;
    if (b < 8064) {
        int z = b / 576, rr = b % 576;
        src = ta.p14[z]; dst = Wbf + (size_t)z * DD_;
        K = 768; N = 768; bx = (rr % 24) * 32; by = (rr / 24) * 32;
    } else if (b < 12672) {
        int bb = b - 8064; int z = bb / 2304, rr = bb % 2304;
        src = ta.f1[z]; dst = Wbf + 14 * DD_ + (size_t)z * 4 * DD_;
        K = 768; N = 3072; bx = (rr % 96) * 32; by = (rr / 96) * 32;
    } else {
        int bb = b - 12672; int z = bb / 2304, rr = bb % 2304;
        src = ta.f2[z]; dst = Wbf + 22 * DD_ + (size_t)z * 4 * DD_;
        K = 3072; N = 768; bx = (rr % 24) * 32; by = (rr / 24) * 32;
    }
    __shared__ float tile[32][33];
    int tx = threadIdx.x & 31, ty = threadIdx.x >> 5;
    #pragma unroll
    for (int i = 0; i < 32; i += 8)
        tile[ty + i][tx] = src[(size_t)(by + ty + i) * N + bx + tx];
    __syncthreads();
    #pragma unroll
    for (int i = 0; i < 32; i += 8)
        dst[(size_t)(bx + ty + i) * K + by + tx] = (__bf16)tile[tx][ty + i];
}

// ============ generic templated MFMA GEMM (BK=64, swizzle, opt split-K) ========
// split-K via gridDim.z: z=0 writes Cf (+bias), z=1 writes Cf2 (no bias);
// partials summed by add_ln_kernel.
template<int TMv, int TNv>
__global__ __launch_bounds__(256) void mfma_gemm_t(
    const __bf16* __restrict__ A, const __bf16* __restrict__ Bt,
    const float* __restrict__ bias, float* __restrict__ Cf,
    float* __restrict__ Cf2, __bf16* __restrict__ Cb,
    int M, int N, int K, float scale, int act)
{
    constexpr int AM = TMv / 32, AN = TNv / 32;
    constexpr int LA = TMv / 32, LB = TNv / 32;
    __shared__ __align__(16) __bf16 As[TMv * TK];
    __shared__ __align__(16) __bf16 Bs[TNv * TK];
    int t = threadIdx.x;
    int wave = t >> 6, lane = t & 63;
    int bm = blockIdx.x * TMv, bn = blockIdx.y * TNv;
    int wm = (wave & 1) * (TMv / 2), wn = (wave >> 1) * (TNv / 2);
    int kz = blockIdx.z;
    int kn = K / (int)gridDim.z, kbeg = kz * kn;
    float* Cfo = (kz == 0) ? Cf : Cf2;

    floatx4 acc[AM][AN];
    #pragma unroll
    for (int i = 0; i < AM; i++)
        #pragma unroll
        for (int j = 0; j < AN; j++) { floatx4 z = {0.f,0.f,0.f,0.f}; acc[i][j] = z; }

    const int mrow = lane & 15, kq = (lane >> 4) * 8;
    const int tr8 = lane >> 3, c8 = lane & 7;
    const int scol = (c8 ^ tr8) * 8;
    const int swz = (lane & 7) << 3;
    const __bf16* aBase = A  + (size_t)(bm + wave * 8 + tr8) * K + scol;
    const __bf16* bBase = Bt + (size_t)(bn + wave * 8 + tr8) * K + scol;

    for (int k0 = kbeg; k0 < kbeg + kn; k0 += TK) {
        __syncthreads();
        #pragma unroll
        for (int i = 0; i < LA; i++)
            async16(aBase + k0 + (size_t)i * 32 * K, &As[(size_t)(i * 256 + wave * 64) * 8]);
        #pragma unroll
        for (int i = 0; i < LB; i++)
            async16(bBase + k0 + (size_t)i * 32 * K, &Bs[(size_t)(i * 256 + wave * 64) * 8]);
        __builtin_amdgcn_s_waitcnt(0x0f70);
        __syncthreads();
        #pragma unroll
        for (int ks = 0; ks < 2; ks++) {
            const int e = (ks * 32 + kq) ^ swz;
            bf16x8 af[AM], bfr[AN];
            #pragma unroll
            for (int mt = 0; mt < AM; mt++)
                af[mt] = *(const bf16x8*)&As[(wm + mt * 16 + mrow) * TK + e];
            #pragma unroll
            for (int nt = 0; nt < AN; nt++)
                bfr[nt] = *(const bf16x8*)&Bs[(wn + nt * 16 + mrow) * TK + e];
            #pragma unroll
            for (int mt = 0; mt < AM; mt++)
                #pragma unroll
                for (int nt = 0; nt < AN; nt++)
                    acc[mt][nt] = __builtin_amdgcn_mfma_f32_16x16x32_bf16(
                        af[mt], bfr[nt], acc[mt][nt], 0, 0, 0);
        }
    }

    int col_l = lane & 15, row_l = (lane >> 4) * 4;
    #pragma unroll
    for (int nt = 0; nt < AN; nt++) {
        int col = bn + wn + nt * 16 + col_l;
        float bs = (kz == 0) ? bias[col] : 0.f;
        #pragma unroll
        for (int mt = 0; mt < AM; mt++) {
            floatx4 v = acc[mt][nt];
            int row0 = bm + wm + mt * 16 + row_l;
            #pragma unroll
            for (int rr = 0; rr < 4; rr++) {
                float o = (v[rr] + bs) * scale;
                if (act) o = gelu_f(o);
                if (Cfo) Cfo[(size_t)(row0 + rr) * N + col] = o;
                if (Cb) Cb[(size_t)(row0 + rr) * N + col] = (__bf16)o;
            }
        }
    }
}

// ====== fused 5-way projection GEMM (q|k|v|kg|vg) + qg gather tiles (y>=30) ====
__global__ __launch_bounds__(256) void mfma_gemm_proj(
    const __bf16* __restrict__ A, const __bf16* __restrict__ Bt,
    const float* __restrict__ bias,
    __bf16* __restrict__ qb, __bf16* __restrict__ kb,
    __bf16* __restrict__ vb, __bf16* __restrict__ vtg,
    __bf16* __restrict__ kgb, __bf16* __restrict__ vgt, int K,
    const __bf16* __restrict__ Wqg_bt, const float* __restrict__ bqg,
    const int* __restrict__ clss, __bf16* __restrict__ qgbb)
{
    __shared__ __align__(16) __bf16 As[128 * TK];
    __shared__ __align__(16) __bf16 Bs[128 * TK];
    int t = threadIdx.x;
    int wave = t >> 6, lane = t & 63;
    const int mrow = lane & 15, kq = (lane >> 4) * 8;
    const int tr8 = lane >> 3, c8 = lane & 7;
    const int scol = (c8 ^ tr8) * 8;
    const int swz = (lane & 7) << 3;
    int col_l = lane & 15, row_l = (lane >> 4) * 4;

    if (blockIdx.y >= 30) {
        // ---- qg: 64 gathered rows x 128 cols (only x==0 does work) ----
        if (blockIdx.x != 0) return;
        int bn = (blockIdx.y - 30) * 128;
        int wm = (wave & 1) * 32, wn = (wave >> 1) * 64;
        int arow0 = wave * 8 + tr8;
        int g0 = clss[arow0], g1 = clss[32 + arow0];
        const __bf16* a0 = A + (size_t)g0 * DIM + scol;
        const __bf16* a1 = A + (size_t)g1 * DIM + scol;
        const __bf16* bBase = Wqg_bt + (size_t)(bn + wave * 8 + tr8) * DIM + scol;

        floatx4 acc[2][4];
        #pragma unroll
        for (int i = 0; i < 2; i++)
            #pragma unroll
            for (int j = 0; j < 4; j++) { floatx4 z = {0.f,0.f,0.f,0.f}; acc[i][j] = z; }

        for (int k0 = 0; k0 < DIM; k0 += TK) {
            __syncthreads();
            async16(a0 + k0, &As[(size_t)(wave * 64) * 8]);
            async16(a1 + k0, &As[(size_t)(256 + wave * 64) * 8]);
            #pragma unroll
            for (int i = 0; i < 4; i++)
                async16(bBase + k0 + (size_t)i * 32 * DIM, &Bs[(size_t)(i * 256 + wave * 64) * 8]);
            __builtin_amdgcn_s_waitcnt(0x0f70);
            __syncthreads();
            #pragma unroll
            for (int ks = 0; ks < 2; ks++) {
                const int e = (ks * 32 + kq) ^ swz;
                bf16x8 af[2], bfr[4];
                #pragma unroll
                for (int mt = 0; mt < 2; mt++)
                    af[mt] = *(const bf16x8*)&As[(wm + mt * 16 + mrow) * TK + e];
                #pragma unroll
                for (int nt = 0; nt < 4; nt++)
                    bfr[nt] = *(const bf16x8*)&Bs[(wn + nt * 16 + mrow) * TK + e];
                #pragma unroll
                for (int mt = 0; mt < 2; mt++)
                    #pragma unroll
                    for (int nt = 0; nt < 4; nt++)
                        acc[mt][nt] = __builtin_amdgcn_mfma_f32_16x16x32_bf16(
                            af[mt], bfr[nt], acc[mt][nt], 0, 0, 0);
            }
        }
        #pragma unroll
        for (int nt = 0; nt < 4; nt++) {
            int col = bn + wn + nt * 16 + col_l;
            float bs = bqg[col];
            #pragma unroll
            for (int mt = 0; mt < 2; mt++) {
                floatx4 v = acc[mt][nt];
                int row0 = wm + mt * 16 + row_l;
                #pragma unroll
                for (int rr = 0; rr < 4; rr++)
                    qgbb[(size_t)(row0 + rr) * DIM + col] = (__bf16)((v[rr] + bs) * QSC2);
            }
        }
        return;
    }

    int bm = blockIdx.x * 128, bn = blockIdx.y * 128;
    int wm = (wave & 1) * 64, wn = (wave >> 1) * 64;

    floatx4 acc[4][4];
    #pragma unroll
    for (int i = 0; i < 4; i++)
        #pragma unroll
        for (int j = 0; j < 4; j++) { floatx4 z = {0.f,0.f,0.f,0.f}; acc[i][j] = z; }

    const __bf16* aBase = A  + (size_t)(bm + wave * 8 + tr8) * K + scol;
    const __bf16* bBase = Bt + (size_t)(bn + wave * 8 + tr8) * K + scol;

    for (int k0 = 0; k0 < K; k0 += TK) {
        __syncthreads();
        #pragma unroll
        for (int i = 0; i < 4; i++) {
            async16(aBase + k0 + (size_t)i * 32 * K, &As[(size_t)(i * 256 + wave * 64) * 8]);
            async16(bBase + k0 + (size_t)i * 32 * K, &Bs[(size_t)(i * 256 + wave * 64) * 8]);
        }
        __builtin_amdgcn_s_waitcnt(0x0f70);
        __syncthreads();
        #pragma unroll
        for (int ks = 0; ks < 2; ks++) {
            const int e = (ks * 32 + kq) ^ swz;
            bf16x8 af[4], bfr[4];
            #pragma unroll
            for (int mt = 0; mt < 4; mt++)
                af[mt] = *(const bf16x8*)&As[(wm + mt * 16 + mrow) * TK + e];
            #pragma unroll
            for (int nt = 0; nt < 4; nt++)
                bfr[nt] = *(const bf16x8*)&Bs[(wn + nt * 16 + mrow) * TK + e];
            #pragma unroll
            for (int mt = 0; mt < 4; mt++)
                #pragma unroll
                for (int nt = 0; nt < 4; nt++)
                    acc[mt][nt] = __builtin_amdgcn_mfma_f32_16x16x32_bf16(
                        af[mt], bfr[nt], acc[mt][nt], 0, 0, 0);
        }
    }

    int seg = bn / 768;                      // 0=q 1=k 2=v 3=kg 4=vg
    int colw_base = bn - seg * 768 + wn;
    float scl = (seg == 0) ? QSC2 : 1.0f;
    #pragma unroll
    for (int nt = 0; nt < 4; nt++) {
        int col = bn + wn + nt * 16 + col_l;
        int colw = colw_base + nt * 16 + col_l;
        float bs = bias[col];
        #pragma unroll
        for (int mt = 0; mt < 4; mt++) {
            floatx4 v = acc[mt][nt];
            int row0 = bm + wm + mt * 16 + row_l;
            __bf16 t4[4];
            #pragma unroll
            for (int rr = 0; rr < 4; rr++) t4[rr] = (__bf16)((v[rr] + bs) * scl);
            if (seg <= 2 || seg == 3) {
                __bf16* dst = (seg == 0) ? qb : (seg == 1) ? kb : (seg == 2) ? vb : kgb;
                #pragma unroll
                for (int rr = 0; rr < 4; rr++)
                    dst[(size_t)(row0 + rr) * 768 + colw] = t4[rr];
            }
            if (seg == 2)
                *(uint2*)&vtg[(size_t)colw * SEQ + row0] = *(uint2*)t4;
            if (seg == 4)
                *(uint2*)&vgt[(size_t)colw * SEQ + row0] = *(uint2*)t4;
        }
    }
}

// ========= unified attention: band full-pass (z<2) + gq flash (z>=2) ==========
// Band blocks iterate all 11 KV tiles and write normalized bf16 rows directly
// to outb (non-global rows). gq partials merged by gq_finalize (global rows).
__global__ __launch_bounds__(256) void attn_kernel(
    const __bf16* __restrict__ qb, const __bf16* __restrict__ kb,
    const __bf16* __restrict__ vb, const __bf16* __restrict__ vtg,
    const __bf16* __restrict__ qgbb, const __bf16* __restrict__ kgb,
    const __bf16* __restrict__ vgt,
    const int* __restrict__ clss, const int* __restrict__ mask_src,
    const int* __restrict__ is_glb,
    float* __restrict__ OpartG, float* __restrict__ mlpartG,
    __bf16* __restrict__ outb)
{
    __shared__ __align__(16) __bf16 Kt[4096];
    __shared__ __align__(16) __bf16 Vt[4096];
    __shared__ __align__(16) __bf16 Ps[4][32 * PS_LD];
    __shared__ int kvalid[64];
    __shared__ int gpos[64];

    const int hh = blockIdx.y;
    const int t = threadIdx.x, wave = t >> 6, lane = t & 63;
    const int quad = lane >> 4, col_l = lane & 15, row_l = quad * 4;
    const int l3 = lane & 3, l2h = lane >> 2, l7 = lane & 7, l3h = lane >> 3;
    __bf16* PsW = Ps[wave];

    if (blockIdx.z >= 2) {
        // ---------- gq flash: split sp over 32, 4 waves x 16 queries ----------
        const int sp = blockIdx.x * 2 + (blockIdx.z - 2);
        bf16x8 aq[2];
        {
            const __bf16* qp = qgbb + (size_t)(wave * 16 + col_l) * DIM + hh * HDIM;
            aq[0] = *(const bf16x8*)(qp + quad * 8);
            aq[1] = *(const bf16x8*)(qp + 32 + quad * 8);
        }
        floatx4 oacc[4];
        #pragma unroll
        for (int i = 0; i < 4; i++) { floatx4 z = {0.f,0.f,0.f,0.f}; oacc[i] = z; }
        float m4[4], l4[4];
        #pragma unroll
        for (int r = 0; r < 4; r++) { m4[r] = -1e30f; l4[r] = 0.f; }

        for (int tt = 0; tt < 2; tt++) {
            int pos0 = sp * 128 + tt * 64;
            __syncthreads();
            if (t < 64) kvalid[t] = (mask_src[pos0 + t] > 0) ? 1 : 0;
            #pragma unroll
            for (int ii = 0; ii < 2; ii++) {
                int gid = wave * 2 + ii;
                int p = gid >> 2, kbase = (gid & 3) * 16;
                async16(kgb + (size_t)(pos0 + kbase + l2h) * DIM + hh * HDIM + p * 32 + l3 * 8,
                        &Kt[p * 2048 + kbase * 32]);
            }
            #pragma unroll
            for (int ii = 0; ii < 2; ii++) {
                int gid = wave * 2 + ii;
                int p = gid >> 2, dbase = (gid & 3) * 16;
                async16(vgt + (size_t)(hh * HDIM + dbase + l2h) * SEQ + pos0 + p * 32 + l3 * 8,
                        &Vt[p * 2048 + dbase * 32]);
            }
            __builtin_amdgcn_s_waitcnt(0x0f70);
            __syncthreads();

            floatx4 s[4];
            #pragma unroll
            for (int nt = 0; nt < 4; nt++) {
                bf16x8 b0 = *(const bf16x8*)&Kt[(nt * 16 + col_l) * 32 + quad * 8];
                bf16x8 b1 = *(const bf16x8*)&Kt[2048 + (nt * 16 + col_l) * 32 + quad * 8];
                floatx4 z = {0.f,0.f,0.f,0.f};
                z = __builtin_amdgcn_mfma_f32_16x16x32_bf16(aq[0], b0, z, 0,0,0);
                z = __builtin_amdgcn_mfma_f32_16x16x32_bf16(aq[1], b1, z, 0,0,0);
                s[nt] = z;
            }
            #pragma unroll
            for (int nt = 0; nt < 4; nt++) {
                int kvv = kvalid[nt * 16 + col_l];
                #pragma unroll
                for (int rr = 0; rr < 4; rr++)
                    if (!kvv) s[nt][rr] = -1e30f;
            }
            #pragma unroll
            for (int rr = 0; rr < 4; rr++) {
                float rm = fmaxf(fmaxf(s[0][rr], s[1][rr]), fmaxf(s[2][rr], s[3][rr]));
                rm = fmaxf(rm, __shfl_xor(rm, 1));
                rm = fmaxf(rm, __shfl_xor(rm, 2));
                rm = fmaxf(rm, __shfl_xor(rm, 4));
                rm = fmaxf(rm, __shfl_xor(rm, 8));
                float mo = m4[rr];
                float mn = fmaxf(mo, rm);
                float alpha = exp2f(mo - mn);
                float rsum = 0.f;
                #pragma unroll
                for (int nt = 0; nt < 4; nt++) {
                    float p = exp2f(s[nt][rr] - mn);
                    rsum += p;
                    PsW[(row_l + rr) * PS_LD + nt * 16 + col_l] = (__bf16)p;
                }
                rsum += __shfl_xor(rsum, 1);
                rsum += __shfl_xor(rsum, 2);
                rsum += __shfl_xor(rsum, 4);
                rsum += __shfl_xor(rsum, 8);
                l4[rr] = l4[rr] * alpha + rsum;
                m4[rr] = mn;
                #pragma unroll
                for (int nt = 0; nt < 4; nt++) oacc[nt][rr] *= alpha;
            }
            bf16x8 ap0 = *(const bf16x8*)&PsW[col_l * PS_LD + quad * 8];
            bf16x8 ap1 = *(const bf16x8*)&PsW[col_l * PS_LD + 32 + quad * 8];
            #pragma unroll
            for (int nt = 0; nt < 4; nt++) {
                bf16x8 b0 = *(const bf16x8*)&Vt[(nt * 16 + col_l) * 32 + quad * 8];
                bf16x8 b1 = *(const bf16x8*)&Vt[2048 + (nt * 16 + col_l) * 32 + quad * 8];
                oacc[nt] = __builtin_amdgcn_mfma_f32_16x16x32_bf16(ap0, b0, oacc[nt], 0,0,0);
                oacc[nt] = __builtin_amdgcn_mfma_f32_16x16x32_bf16(ap1, b1, oacc[nt], 0,0,0);
            }
        }
        size_t base = (size_t)(hh * 32 + sp) * 64;
        #pragma unroll
        for (int nt = 0; nt < 4; nt++)
            #pragma unroll
            for (int rr = 0; rr < 4; rr++)
                OpartG[(base + wave * 16 + row_l + rr) * 64 + nt * 16 + col_l] = oacc[nt][rr];
        if (col_l == 0) {
            #pragma unroll
            for (int rr = 0; rr < 4; rr++) {
                mlpartG[(base + wave * 16 + row_l + rr) * 2]     = m4[rr];
                mlpartG[(base + wave * 16 + row_l + rr) * 2 + 1] = l4[rr];
            }
        }
        return;
    }

    // ---------- band + global-key flash: full pass (11 tiles) ----------
    const int n = blockIdx.x, qh = blockIdx.z;
    const int qw = qh * 128 + wave * 32;

    if (t < 64) gpos[t] = clss[t];

    bf16x8 aq[2][2];
    #pragma unroll
    for (int mt = 0; mt < 2; mt++) {
        const __bf16* qp = qb + (size_t)(n * CHK + qw + mt * 16 + col_l) * DIM + hh * HDIM;
        aq[mt][0] = *(const bf16x8*)(qp + quad * 8);
        aq[mt][1] = *(const bf16x8*)(qp + 32 + quad * 8);
    }

    floatx4 oacc[2][4];
    #pragma unroll
    for (int i = 0; i < 2; i++)
        #pragma unroll
        for (int j = 0; j < 4; j++) { floatx4 z = {0.f,0.f,0.f,0.f}; oacc[i][j] = z; }
    float mrw[8], lrw[8];
    #pragma unroll
    for (int r = 0; r < 8; r++) { mrw[r] = -1e30f; lrw[r] = 0.f; }

    for (int tt = 0; tt < 11; tt++) {
        __syncthreads();
        int jbase = -1;
        int isglob = (tt == 0);
        if (isglob) {
            if (t < 64) kvalid[t] = (mask_src[gpos[t]] > 0) ? 1 : 0;
            #pragma unroll
            for (int g = 0; g < 2; g++) {
                int gid = wave * 2 + g;
                int p = gid >> 2, kbase = (gid & 3) * 16;
                int pos = gpos[kbase + l2h];
                async16(kb + (size_t)pos * DIM + hh * HDIM + p * 32 + l3 * 8,
                        &Kt[p * 2048 + kbase * 32]);
            }
            __bf16* Vrow = &Ps[0][0];
            #pragma unroll
            for (int g = 0; g < 2; g++) {
                int cg = wave * 2 + g;
                int pos = gpos[cg * 8 + l3h];
                async16(vb + (size_t)pos * DIM + hh * HDIM + l7 * 8,
                        &Vrow[cg * 64 * 8]);
            }
        } else {
            int jt = qh * 2 + tt - 1;
            jbase = jt * 64;
            if (t < 64) {
                int pos = n * CHK + jbase + t - CHK;
                kvalid[t] = (pos >= 0 && pos < SEQ && mask_src[pos] > 0
                             && is_glb[pos] == 0) ? 1 : 0;
            }
            int s0 = n * CHK + jbase - CHK;
            #pragma unroll
            for (int g = 0; g < 2; g++) {
                int gid = wave * 2 + g;
                int p = gid >> 2, kbase = (gid & 3) * 16;
                int pos = s0 + kbase + l2h; pos = min(max(pos, 0), SEQ - 1);
                async16(kb + (size_t)pos * DIM + hh * HDIM + p * 32 + l3 * 8,
                        &Kt[p * 2048 + kbase * 32]);
            }
            #pragma unroll
            for (int g = 0; g < 2; g++) {
                int gid = wave * 2 + g;
                int p = gid >> 2, dbase = (gid & 3) * 16;
                int d = dbase + l2h;
                int s = s0 + p * 32 + l3 * 8; s = min(max(s, 0), SEQ - 8);
                async16(vtg + (size_t)(hh * HDIM + d) * SEQ + s,
                        &Vt[p * 2048 + dbase * 32]);
            }
        }
        __builtin_amdgcn_s_waitcnt(0x0f70);
        __syncthreads();
        if (isglob) {
            const __bf16* Vrow = &Ps[0][0];
            for (int idx = t; idx < 4096; idx += 256) {
                int key = idx >> 6, d = idx & 63;
                Vt[(key >> 5) * 2048 + d * 32 + (key & 31)] = Vrow[idx];
            }
            __syncthreads();
        } else {
            if (jbase + 63 < qw || jbase > qw + 543) continue;
        }

        bf16x8 bkf[4][2];
        #pragma unroll
        for (int nt = 0; nt < 4; nt++) {
            bkf[nt][0] = *(const bf16x8*)&Kt[(nt * 16 + col_l) * 32 + quad * 8];
            bkf[nt][1] = *(const bf16x8*)&Kt[2048 + (nt * 16 + col_l) * 32 + quad * 8];
        }
        int kv[4];
        #pragma unroll
        for (int nt = 0; nt < 4; nt++) kv[nt] = kvalid[nt * 16 + col_l];

        #pragma unroll
        for (int mt = 0; mt < 2; mt++) {
            floatx4 s[4];
            #pragma unroll
            for (int nt = 0; nt < 4; nt++) {
                floatx4 z = {0.f,0.f,0.f,0.f};
                z = __builtin_amdgcn_mfma_f32_16x16x32_bf16(aq[mt][0], bkf[nt][0], z, 0,0,0);
                z = __builtin_amdgcn_mfma_f32_16x16x32_bf16(aq[mt][1], bkf[nt][1], z, 0,0,0);
                s[nt] = z;
            }
            #pragma unroll
            for (int nt = 0; nt < 4; nt++)
                #pragma unroll
                for (int rr = 0; rr < 4; rr++) {
                    int ok = kv[nt];
                    if (!isglob) {
                        int i = qw + mt * 16 + row_l + rr;
                        int rel = jbase + nt * 16 + col_l - i;
                        ok = ok && (rel >= 0) && (rel <= 2 * WINR);
                    }
                    if (!ok) s[nt][rr] = -1e30f;
                }
            #pragma unroll
            for (int rr = 0; rr < 4; rr++) {
                float rm = fmaxf(fmaxf(s[0][rr], s[1][rr]), fmaxf(s[2][rr], s[3][rr]));
                rm = fmaxf(rm, __shfl_xor(rm, 1));
                rm = fmaxf(rm, __shfl_xor(rm, 2));
                rm = fmaxf(rm, __shfl_xor(rm, 4));
                rm = fmaxf(rm, __shfl_xor(rm, 8));
                int ri = mt * 4 + rr;
                float mo = mrw[ri];
                float mn = fmaxf(mo, rm);
                float alpha = exp2f(mo - mn);
                float rsum = 0.f;
                #pragma unroll
                for (int nt = 0; nt < 4; nt++) {
                    float p = exp2f(s[nt][rr] - mn);
                    rsum += p;
                    PsW[(mt * 16 + row_l + rr) * PS_LD + nt * 16 + col_l] = (__bf16)p;
                }
                rsum += __shfl_xor(rsum, 1);
                rsum += __shfl_xor(rsum, 2);
                rsum += __shfl_xor(rsum, 4);
                rsum += __shfl_xor(rsum, 8);
                lrw[ri] = lrw[ri] * alpha + rsum;
                mrw[ri] = mn;
                #pragma unroll
                for (int nt = 0; nt < 4; nt++) oacc[mt][nt][rr] *= alpha;
            }
        }
        bf16x8 bvf[4][2], ap[2][2];
        #pragma unroll
        for (int nt = 0; nt < 4; nt++) {
            bvf[nt][0] = *(const bf16x8*)&Vt[(nt * 16 + col_l) * 32 + quad * 8];
            bvf[nt][1] = *(const bf16x8*)&Vt[2048 + (nt * 16 + col_l) * 32 + quad * 8];
        }
        #pragma unroll
        for (int mt = 0; mt < 2; mt++) {
            ap[mt][0] = *(const bf16x8*)&PsW[(mt * 16 + col_l) * PS_LD + quad * 8];
            ap[mt][1] = *(const bf16x8*)&PsW[(mt * 16 + col_l) * PS_LD + 32 + quad * 8];
        }
        #pragma unroll
        for (int mt = 0; mt < 2; mt++)
            #pragma unroll
            for (int nt = 0; nt < 4; nt++) {
                oacc[mt][nt] = __builtin_amdgcn_mfma_f32_16x16x32_bf16(
                    ap[mt][0], bvf[nt][0], oacc[mt][nt], 0,0,0);
                oacc[mt][nt] = __builtin_amdgcn_mfma_f32_16x16x32_bf16(
                    ap[mt][1], bvf[nt][1], oacc[mt][nt], 0,0,0);
            }
    }

    // normalized bf16 write, skipping global rows (gq_finalize owns those)
    #pragma unroll
    for (int mt = 0; mt < 2; mt++) {
        #pragma unroll
        for (int rr = 0; rr < 4; rr++) {
            int srow = n * CHK + qw + mt * 16 + row_l + rr;
            if (is_glb[srow]) continue;
            float inv = 1.0f / lrw[mt * 4 + rr];
            #pragma unroll
            for (int nt = 0; nt < 4; nt++)
                outb[(size_t)srow * DIM + hh * HDIM + nt * 16 + col_l] =
                    (__bf16)(oacc[mt][nt][rr] * inv);
        }
    }
}

// ---------------- gq finalize: 32-way merge for the 64 global rows -------------
__global__ __launch_bounds__(64) void gq_finalize(
    const float* __restrict__ OpartG, const float* __restrict__ mlpartG,
    const int* __restrict__ clss, __bf16* __restrict__ outb)
{
    int r = blockIdx.x, hh = blockIdx.y, d = threadIdx.x;
    float M = -1e30f;
    for (int sp = 0; sp < 32; sp++)
        M = fmaxf(M, mlpartG[(((size_t)hh * 32 + sp) * 64 + r) * 2]);
    float L = 0.f, acc = 0.f;
    for (int sp = 0; sp < 32; sp++) {
        size_t b = ((size_t)hh * 32 + sp) * 64 + r;
        float w = exp2f(mlpartG[b * 2] - M);
        L += mlpartG[b * 2 + 1] * w;
        acc += w * OpartG[b * 64 + d];
    }
    int pos = clss[r];
    outb[(size_t)pos * DIM + hh * HDIM + d] = (__bf16)(acc / L);
}

// ---------------- host launcher ----------------
extern "C" void kernel_launch(void* const* d_in, const int* in_sizes, int n_in,
                              void* d_out, int out_size, void* d_ws, size_t ws_size,
                              hipStream_t stream)
{
    const int* x        = (const int*)d_in[0];
    const int* mask_src = (const int*)d_in[1];
    const int* clss     = (const int*)d_in[2];
    const int* segs     = (const int*)d_in[3];
    const float* word_emb = (const float*)d_in[4];
    const float* pos_emb  = (const float*)d_in[5];
    const float* type_emb = (const float*)d_in[6];
    const float* ln_e_s   = (const float*)d_in[7];
    const float* ln_e_b   = (const float*)d_in[8];
    const float* Wq  = (const float*)d_in[9];
    const float* bq  = (const float*)d_in[10];
    const float* Wk  = (const float*)d_in[11];
    const float* bk  = (const float*)d_in[12];
    const float* Wv  = (const float*)d_in[13];
    const float* bv  = (const float*)d_in[14];
    const float* Wqg = (const float*)d_in[15];
    const float* bqg = (const float*)d_in[16];
    const float* Wkg = (const float*)d_in[17];
    const float* bkg = (const float*)d_in[18];
    const float* Wvg = (const float*)d_in[19];
    const float* bvg = (const float*)d_in[20];
    const float* Wo  = (const float*)d_in[21];
    const float* bo  = (const float*)d_in[22];
    const float* ln1_s = (const float*)d_in[23];
    const float* ln1_b = (const float*)d_in[24];
    const float* Wf1 = (const float*)d_in[25];
    const float* bf1 = (const float*)d_in[26];
    const float* Wf2 = (const float*)d_in[27];
    const float* bf2 = (const float*)d_in[28];
    const float* ln2_s = (const float*)d_in[29];
    const float* ln2_b = (const float*)d_in[30];

    const size_t DD = (size_t)DIM * DIM;
    float* ws = (float*)d_ws;
    float*  h    = ws;
    float*  s4   = ws + SD;
    __bf16* hb   = (__bf16*)(ws + 2 * SD);
    __bf16* b6b  = (__bf16*)(ws + 2 * SD) + SD;
    __bf16* qb   = (__bf16*)(ws + 3 * SD);
    __bf16* kb   = (__bf16*)(ws + 3 * SD) + SD;
    __bf16* vb   = (__bf16*)(ws + 4 * SD);
    __bf16* vtg  = (__bf16*)(ws + 4 * SD) + SD;
    __bf16* kgb  = (__bf16*)(ws + 5 * SD);
    __bf16* vgt  = (__bf16*)(ws + 5 * SD) + SD;
    __bf16* gelu_b = qb;
    float* extra = ws + 6 * SD;
    __bf16* Wbf   = (__bf16*)extra;                     // 30*DD bf16
    float* after_w = extra + 15 * DD;
    float* bqkv   = after_w;                            // 2*3840
    float* OpartG = bqkv + 7680;                        // 12*32*64*64 = 1,572,864
    float* mlpartG= OpartG + 1572864;                   // 49,152
    float* s4b    = mlpartG + 49152;                    // SD (split-K partial)
    __bf16* qgbb  = (__bf16*)(s4b + SD);                // 64*768 bf16
    int*   isglb  = (int*)(qgbb + (size_t)NCLS * DIM);  // SEQ

    embed_ln_kernel<<<SEQ / 4, 256, 0, stream>>>(x, segs, word_emb, pos_emb, type_emb,
                                                 ln_e_s, ln_e_b, h, hb, isglb);
    set_rank_kernel<<<1, 64, 0, stream>>>(clss, isglb);
    {
        TArgs ta{};
        ta.p14[0] = Wq;        ta.p14[1] = Wk;        ta.p14[2] = Wv;
        ta.p14[3] = Wkg;       ta.p14[4] = Wvg;
        ta.p14[5] = Wq + DD;   ta.p14[6] = Wk + DD;   ta.p14[7] = Wv + DD;
        ta.p14[8] = Wkg + DD;  ta.p14[9] = Wvg + DD;
        ta.p14[10] = Wo;       ta.p14[11] = Wo + DD;
        ta.p14[12] = Wqg;      ta.p14[13] = Wqg + DD;
        ta.f1[0] = Wf1; ta.f1[1] = Wf1 + (size_t)DIM * FFD;
        ta.f2[0] = Wf2; ta.f2[1] = Wf2 + (size_t)FFD * DIM;
        tpose_setup_kernel<<<17310, 256, 0, stream>>>(ta, Wbf, bq, bk, bv, bkg, bvg, bqkv);
    }

    for (int l = 0; l < NLAYER; l++) {
        const float* bqg_l = bqg + (size_t)l * DIM;
        const float* bo_l  = bo  + (size_t)l * DIM;
        const float* bf1_l = bf1 + (size_t)l * FFD;
        const float* bf2_l = bf2 + (size_t)l * DIM;

        // fused 5-way projection + qg gather tiles (y>=30)
        mfma_gemm_proj<<<dim3(SEQ / 128, 36), 256, 0, stream>>>(
            hb, Wbf + (size_t)l * 5 * DD, bqkv + l * 3840,
            qb, kb, vb, vtg, kgb, vgt, DIM,
            Wbf + 12 * DD + (size_t)l * DD, bqg_l, clss, qgbb);
        // unified band (full-pass, direct bf16 out) + gq attention
        attn_kernel<<<dim3(NCHK, NH, 4), 256, 0, stream>>>(
            qb, kb, vb, vtg, qgbb, kgb, vgt, clss, mask_src, isglb,
            OpartG, mlpartG, b6b);
        gq_finalize<<<dim3(NCLS, NH), 64, 0, stream>>>(OpartG, mlpartG, clss, b6b);
        // output projection (split-K=2) + LN1
        mfma_gemm_t<128, 64><<<dim3(SEQ / 128, DIM / 64, 2), 256, 0, stream>>>(
            b6b, Wbf + 10 * DD + (size_t)l * DD, bo_l, s4, s4b, nullptr,
            SEQ, DIM, DIM, 1.0f, 0);
        add_ln_kernel<<<SEQ / 4, 256, 0, stream>>>(h, s4, s4b, ln1_s + (size_t)l * DIM,
                                                   ln1_b + (size_t)l * DIM, h, hb);
        // FFN
        mfma_gemm_t<128, 128><<<dim3(SEQ / 128, FFD / 128, 1), 256, 0, stream>>>(
            hb, Wbf + 14 * DD + (size_t)l * 4 * DD, bf1_l, nullptr, nullptr, gelu_b,
            SEQ, FFD, DIM, 1.0f, 1);
        mfma_gemm_t<128, 64><<<dim3(SEQ / 128, DIM / 64, 2), 256, 0, stream>>>(
            gelu_b, Wbf + 22 * DD + (size_t)l * 4 * DD, bf2_l, s4, s4b, nullptr,
            SEQ, DIM, FFD, 1.0f, 0);
        add_ln_kernel<<<SEQ / 4, 256, 0, stream>>>(h, s4, s4b, ln2_s + (size_t)l * DIM,
                                                   ln2_b + (size_t)l * DIM,
                                                   (l == NLAYER - 1) ? (float*)d_out : h, hb);
    }
}

// Round 3
// 698.968 us; speedup vs baseline: 1.2355x; 1.0327x over previous
//
#include <hip/hip_runtime.h>
#include <hip/hip_bf16.h>
#include <cstdint>

#define SEQ  4096
#define DIM  768
#define NH   12
#define HDIM 64
#define NLAYER 2
#define CHK  256
#define WINR 256
#define NCLS 64
#define NCHK 16
#define FFD  3072
#define QSCALE 0.125f
#define LOG2E 1.44269504f
#define QSC2 (QSCALE * LOG2E)
#define SD ((size_t)SEQ * DIM)
#define PS_LD 72
#define TK 64
#define DEFER_THR 8.0f

typedef __attribute__((__vector_size__(16))) float floatx4;
typedef __attribute__((ext_vector_type(8))) __bf16 bf16x8;
typedef __attribute__((ext_vector_type(4))) __bf16 bf16x4;

__device__ __forceinline__ void async16(const void* g, void* l) {
    __builtin_amdgcn_global_load_lds(
        (const __attribute__((address_space(1))) uint32_t*)g,
        (__attribute__((address_space(3))) uint32_t*)l, 16, 0, 0);
}

__device__ __forceinline__ float gelu_f(float x) {
    float x3 = x * x * x;
    return 0.5f * x * (1.0f + tanhf(0.7978845608028654f * (x + 0.044715f * x3)));
}

// ---------------- embedding + LN (wave-per-row, shuffle reduce) ----------------
__global__ __launch_bounds__(256) void embed_ln_kernel(
    const int* __restrict__ x, const int* __restrict__ segs,
    const float* __restrict__ word_emb, const float* __restrict__ pos_emb,
    const float* __restrict__ type_emb, const float* __restrict__ gs,
    const float* __restrict__ gb, float* __restrict__ h, __bf16* __restrict__ hb,
    int* __restrict__ isglb)
{
    int wave = threadIdx.x >> 6, lane = threadIdx.x & 63;
    int s = blockIdx.x * 4 + wave;
    if (lane == 0) isglb[s] = 0;
    int w = x[s], sg = segs[s];
    const float4* wp = (const float4*)(word_emb + (size_t)w * DIM);
    const float4* pp = (const float4*)(pos_emb + (size_t)s * DIM);
    const float4* tp = (const float4*)(type_emb + (size_t)sg * DIM);
    float4 v[3]; float lsum = 0.f;
    #pragma unroll
    for (int i = 0; i < 3; i++) {
        int d4 = lane + i * 64;
        float4 a = wp[d4], b = pp[d4], c = tp[d4];
        float4 r;
        r.x = a.x + b.x + c.x; r.y = a.y + b.y + c.y;
        r.z = a.z + b.z + c.z; r.w = a.w + b.w + c.w;
        v[i] = r; lsum += r.x + r.y + r.z + r.w;
    }
    #pragma unroll
    for (int st = 32; st > 0; st >>= 1) lsum += __shfl_xor(lsum, st);
    float mean = lsum * (1.0f / DIM);
    float lv = 0.f;
    #pragma unroll
    for (int i = 0; i < 3; i++) {
        float dx = v[i].x - mean, dy = v[i].y - mean, dz = v[i].z - mean, dw = v[i].w - mean;
        lv += dx * dx + dy * dy + dz * dz + dw * dw;
    }
    #pragma unroll
    for (int st = 32; st > 0; st >>= 1) lv += __shfl_xor(lv, st);
    float rstd = rsqrtf(lv * (1.0f / DIM) + 1e-5f);
    #pragma unroll
    for (int i = 0; i < 3; i++) {
        int d4 = lane + i * 64;
        float4 s4v = ((const float4*)gs)[d4], b4v = ((const float4*)gb)[d4];
        float4 o;
        o.x = (v[i].x - mean) * rstd * s4v.x + b4v.x;
        o.y = (v[i].y - mean) * rstd * s4v.y + b4v.y;
        o.z = (v[i].z - mean) * rstd * s4v.z + b4v.z;
        o.w = (v[i].w - mean) * rstd * s4v.w + b4v.w;
        ((float4*)(h + (size_t)s * DIM))[d4] = o;
        bf16x4 ob; ob[0] = (__bf16)o.x; ob[1] = (__bf16)o.y;
        ob[2] = (__bf16)o.z; ob[3] = (__bf16)o.w;
        *(bf16x4*)(hb + (size_t)s * DIM + (size_t)d4 * 4) = ob;
    }
}

// ---------------- residual(2) add + LN (wave-per-row) ----------------
__global__ __launch_bounds__(256) void add_ln_kernel(
    const float* __restrict__ h, const float* __restrict__ r,
    const float* __restrict__ r2,
    const float* __restrict__ gs, const float* __restrict__ gb,
    float* __restrict__ hout, __bf16* __restrict__ hb)
{
    int wave = threadIdx.x >> 6, lane = threadIdx.x & 63;
    int s = blockIdx.x * 4 + wave;
    const float4* hp = (const float4*)(h + (size_t)s * DIM);
    const float4* rp = (const float4*)(r + (size_t)s * DIM);
    const float4* rp2 = (const float4*)(r2 + (size_t)s * DIM);
    float4 v[3]; float lsum = 0.f;
    #pragma unroll
    for (int i = 0; i < 3; i++) {
        int d4 = lane + i * 64;
        float4 a = hp[d4], b = rp[d4], c = rp2[d4];
        float4 q;
        q.x = a.x + b.x + c.x; q.y = a.y + b.y + c.y;
        q.z = a.z + b.z + c.z; q.w = a.w + b.w + c.w;
        v[i] = q; lsum += q.x + q.y + q.z + q.w;
    }
    #pragma unroll
    for (int st = 32; st > 0; st >>= 1) lsum += __shfl_xor(lsum, st);
    float mean = lsum * (1.0f / DIM);
    float lv = 0.f;
    #pragma unroll
    for (int i = 0; i < 3; i++) {
        float dx = v[i].x - mean, dy = v[i].y - mean, dz = v[i].z - mean, dw = v[i].w - mean;
        lv += dx * dx + dy * dy + dz * dz + dw * dw;
    }
    #pragma unroll
    for (int st = 32; st > 0; st >>= 1) lv += __shfl_xor(lv, st);
    float rstd = rsqrtf(lv * (1.0f / DIM) + 1e-5f);
    #pragma unroll
    for (int i = 0; i < 3; i++) {
        int d4 = lane + i * 64;
        float4 s4v = ((const float4*)gs)[d4], b4v = ((const float4*)gb)[d4];
        float4 o;
        o.x = (v[i].x - mean) * rstd * s4v.x + b4v.x;
        o.y = (v[i].y - mean) * rstd * s4v.y + b4v.y;
        o.z = (v[i].z - mean) * rstd * s4v.z + b4v.z;
        o.w = (v[i].w - mean) * rstd * s4v.w + b4v.w;
        ((float4*)(hout + (size_t)s * DIM))[d4] = o;
        bf16x4 ob; ob[0] = (__bf16)o.x; ob[1] = (__bf16)o.y;
        ob[2] = (__bf16)o.z; ob[3] = (__bf16)o.w;
        *(bf16x4*)(hb + (size_t)s * DIM + (size_t)d4 * 4) = ob;
    }
}

// ------- merged weight transpose-convert + bias concat + isglb set -------
struct TArgs { const float* p14[14]; const float* f1[2]; const float* f2[2]; };
#define DD_ ((size_t)DIM * DIM)
__global__ __launch_bounds__(256) void tpose_setup_kernel(
    TArgs ta, __bf16* __restrict__ Wbf,
    const float* __restrict__ bq, const float* __restrict__ bk,
    const float* __restrict__ bv, const float* __restrict__ bkg,
    const float* __restrict__ bvg, float* __restrict__ bqkv,
    const int* __restrict__ clss, int* __restrict__ isglb)
{
    int b = blockIdx.x;
    if (b >= 17280) {
        int idx = (b - 17280) * 256 + threadIdx.x;   // 0..7679
        int l = idx / 3840, c = idx % 3840, j = c / 768, d = c % 768;
        const float* s = (j == 0) ? bq : (j == 1) ? bk : (j == 2) ? bv : (j == 3) ? bkg : bvg;
        bqkv[idx] = s[l * 768 + d];
        if (b == 17280 && threadIdx.x < 64) isglb[clss[threadIdx.x]] = 1;
        return;
    }
    const float* src; __bf16* dst; int K, N, bx, by;
    if (b < 8064) {
        int z = b / 576, rr = b % 576;
        src = ta.p14[z]; dst = Wbf + (size_t)z * DD_;
        K = 768; N = 768; bx = (rr % 24) * 32; by = (rr / 24) * 32;
    } else if (b < 12672) {
        int bb = b - 8064; int z = bb / 2304, rr = bb % 2304;
        src = ta.f1[z]; dst = Wbf + 14 * DD_ + (size_t)z * 4 * DD_;
        K = 768; N = 3072; bx = (rr % 96) * 32; by = (rr / 96) * 32;
    } else {
        int bb = b - 12672; int z = bb / 2304, rr = bb % 2304;
        src = ta.f2[z]; dst = Wbf + 22 * DD_ + (size_t)z * 4 * DD_;
        K = 3072; N = 768; bx = (rr % 24) * 32; by = (rr / 24) * 32;
    }
    __shared__ float tile[32][33];
    int tx = threadIdx.x & 31, ty = threadIdx.x >> 5;
    #pragma unroll
    for (int i = 0; i < 32; i += 8)
        tile[ty + i][tx] = src[(size_t)(by + ty + i) * N + bx + tx];
    __syncthreads();
    #pragma unroll
    for (int i = 0; i < 32; i += 8)
        dst[(size_t)(bx + ty + i) * K + by + tx] = (__bf16)tile[tx][ty + i];
}

// ============ generic templated MFMA GEMM (BK=64, swizzle, opt split-K) ========
template<int TMv, int TNv>
__global__ __launch_bounds__(256) void mfma_gemm_t(
    const __bf16* __restrict__ A, const __bf16* __restrict__ Bt,
    const float* __restrict__ bias, float* __restrict__ Cf,
    float* __restrict__ Cf2, __bf16* __restrict__ Cb,
    int M, int N, int K, float scale, int act)
{
    constexpr int AM = TMv / 32, AN = TNv / 32;
    constexpr int LA = TMv / 32, LB = TNv / 32;
    __shared__ __align__(16) __bf16 As[TMv * TK];
    __shared__ __align__(16) __bf16 Bs[TNv * TK];
    int t = threadIdx.x;
    int wave = t >> 6, lane = t & 63;
    int bm = blockIdx.x * TMv, bn = blockIdx.y * TNv;
    int wm = (wave & 1) * (TMv / 2), wn = (wave >> 1) * (TNv / 2);
    int kz = blockIdx.z;
    int kn = K / (int)gridDim.z, kbeg = kz * kn;
    float* Cfo = (kz == 0) ? Cf : Cf2;

    floatx4 acc[AM][AN];
    #pragma unroll
    for (int i = 0; i < AM; i++)
        #pragma unroll
        for (int j = 0; j < AN; j++) { floatx4 z = {0.f,0.f,0.f,0.f}; acc[i][j] = z; }

    const int mrow = lane & 15, kq = (lane >> 4) * 8;
    const int tr8 = lane >> 3, c8 = lane & 7;
    const int scol = (c8 ^ tr8) * 8;
    const int swz = (lane & 7) << 3;
    const __bf16* aBase = A  + (size_t)(bm + wave * 8 + tr8) * K + scol;
    const __bf16* bBase = Bt + (size_t)(bn + wave * 8 + tr8) * K + scol;

    for (int k0 = kbeg; k0 < kbeg + kn; k0 += TK) {
        __syncthreads();
        #pragma unroll
        for (int i = 0; i < LA; i++)
            async16(aBase + k0 + (size_t)i * 32 * K, &As[(size_t)(i * 256 + wave * 64) * 8]);
        #pragma unroll
        for (int i = 0; i < LB; i++)
            async16(bBase + k0 + (size_t)i * 32 * K, &Bs[(size_t)(i * 256 + wave * 64) * 8]);
        __builtin_amdgcn_s_waitcnt(0x0f70);
        __syncthreads();
        #pragma unroll
        for (int ks = 0; ks < 2; ks++) {
            const int e = (ks * 32 + kq) ^ swz;
            bf16x8 af[AM], bfr[AN];
            #pragma unroll
            for (int mt = 0; mt < AM; mt++)
                af[mt] = *(const bf16x8*)&As[(wm + mt * 16 + mrow) * TK + e];
            #pragma unroll
            for (int nt = 0; nt < AN; nt++)
                bfr[nt] = *(const bf16x8*)&Bs[(wn + nt * 16 + mrow) * TK + e];
            #pragma unroll
            for (int mt = 0; mt < AM; mt++)
                #pragma unroll
                for (int nt = 0; nt < AN; nt++)
                    acc[mt][nt] = __builtin_amdgcn_mfma_f32_16x16x32_bf16(
                        af[mt], bfr[nt], acc[mt][nt], 0, 0, 0);
        }
    }

    int col_l = lane & 15, row_l = (lane >> 4) * 4;
    #pragma unroll
    for (int nt = 0; nt < AN; nt++) {
        int col = bn + wn + nt * 16 + col_l;
        float bs = (kz == 0) ? bias[col] : 0.f;
        #pragma unroll
        for (int mt = 0; mt < AM; mt++) {
            floatx4 v = acc[mt][nt];
            int row0 = bm + wm + mt * 16 + row_l;
            #pragma unroll
            for (int rr = 0; rr < 4; rr++) {
                float o = (v[rr] + bs) * scale;
                if (act) o = gelu_f(o);
                if (Cfo) Cfo[(size_t)(row0 + rr) * N + col] = o;
                if (Cb) Cb[(size_t)(row0 + rr) * N + col] = (__bf16)o;
            }
        }
    }
}

// ====== fused 5-way projection GEMM (q|k|v|kg|vg) + qg gather tiles (y>=30) ====
__global__ __launch_bounds__(256) void mfma_gemm_proj(
    const __bf16* __restrict__ A, const __bf16* __restrict__ Bt,
    const float* __restrict__ bias,
    __bf16* __restrict__ qb, __bf16* __restrict__ kb,
    __bf16* __restrict__ vb, __bf16* __restrict__ vtg,
    __bf16* __restrict__ kgb, __bf16* __restrict__ vgt, int K,
    const __bf16* __restrict__ Wqg_bt, const float* __restrict__ bqg,
    const int* __restrict__ clss, __bf16* __restrict__ qgbb,
    const int* __restrict__ is_glb)
{
    __shared__ __align__(16) __bf16 As[128 * TK];
    __shared__ __align__(16) __bf16 Bs[128 * TK];
    int t = threadIdx.x;
    int wave = t >> 6, lane = t & 63;
    const int mrow = lane & 15, kq = (lane >> 4) * 8;
    const int tr8 = lane >> 3, c8 = lane & 7;
    const int scol = (c8 ^ tr8) * 8;
    const int swz = (lane & 7) << 3;
    int col_l = lane & 15, row_l = (lane >> 4) * 4;

    if (blockIdx.y >= 30) {
        // ---- qg: 64 gathered rows x 128 cols (only x==0 does work) ----
        if (blockIdx.x != 0) return;
        int bn = (blockIdx.y - 30) * 128;
        int wm = (wave & 1) * 32, wn = (wave >> 1) * 64;
        int arow0 = wave * 8 + tr8;
        int g0 = clss[arow0], g1 = clss[32 + arow0];
        const __bf16* a0 = A + (size_t)g0 * DIM + scol;
        const __bf16* a1 = A + (size_t)g1 * DIM + scol;
        const __bf16* bBase = Wqg_bt + (size_t)(bn + wave * 8 + tr8) * DIM + scol;

        floatx4 acc[2][4];
        #pragma unroll
        for (int i = 0; i < 2; i++)
            #pragma unroll
            for (int j = 0; j < 4; j++) { floatx4 z = {0.f,0.f,0.f,0.f}; acc[i][j] = z; }

        for (int k0 = 0; k0 < DIM; k0 += TK) {
            __syncthreads();
            async16(a0 + k0, &As[(size_t)(wave * 64) * 8]);
            async16(a1 + k0, &As[(size_t)(256 + wave * 64) * 8]);
            #pragma unroll
            for (int i = 0; i < 4; i++)
                async16(bBase + k0 + (size_t)i * 32 * DIM, &Bs[(size_t)(i * 256 + wave * 64) * 8]);
            __builtin_amdgcn_s_waitcnt(0x0f70);
            __syncthreads();
            #pragma unroll
            for (int ks = 0; ks < 2; ks++) {
                const int e = (ks * 32 + kq) ^ swz;
                bf16x8 af[2], bfr[4];
                #pragma unroll
                for (int mt = 0; mt < 2; mt++)
                    af[mt] = *(const bf16x8*)&As[(wm + mt * 16 + mrow) * TK + e];
                #pragma unroll
                for (int nt = 0; nt < 4; nt++)
                    bfr[nt] = *(const bf16x8*)&Bs[(wn + nt * 16 + mrow) * TK + e];
                #pragma unroll
                for (int mt = 0; mt < 2; mt++)
                    #pragma unroll
                    for (int nt = 0; nt < 4; nt++)
                        acc[mt][nt] = __builtin_amdgcn_mfma_f32_16x16x32_bf16(
                            af[mt], bfr[nt], acc[mt][nt], 0, 0, 0);
            }
        }
        #pragma unroll
        for (int nt = 0; nt < 4; nt++) {
            int col = bn + wn + nt * 16 + col_l;
            float bs = bqg[col];
            #pragma unroll
            for (int mt = 0; mt < 2; mt++) {
                floatx4 v = acc[mt][nt];
                int row0 = wm + mt * 16 + row_l;
                #pragma unroll
                for (int rr = 0; rr < 4; rr++)
                    qgbb[(size_t)(row0 + rr) * DIM + col] = (__bf16)((v[rr] + bs) * QSC2);
            }
        }
        return;
    }

    int bm = blockIdx.x * 128, bn = blockIdx.y * 128;
    int wm = (wave & 1) * 64, wn = (wave >> 1) * 64;

    floatx4 acc[4][4];
    #pragma unroll
    for (int i = 0; i < 4; i++)
        #pragma unroll
        for (int j = 0; j < 4; j++) { floatx4 z = {0.f,0.f,0.f,0.f}; acc[i][j] = z; }

    const __bf16* aBase = A  + (size_t)(bm + wave * 8 + tr8) * K + scol;
    const __bf16* bBase = Bt + (size_t)(bn + wave * 8 + tr8) * K + scol;

    for (int k0 = 0; k0 < K; k0 += TK) {
        __syncthreads();
        #pragma unroll
        for (int i = 0; i < 4; i++) {
            async16(aBase + k0 + (size_t)i * 32 * K, &As[(size_t)(i * 256 + wave * 64) * 8]);
            async16(bBase + k0 + (size_t)i * 32 * K, &Bs[(size_t)(i * 256 + wave * 64) * 8]);
        }
        __builtin_amdgcn_s_waitcnt(0x0f70);
        __syncthreads();
        #pragma unroll
        for (int ks = 0; ks < 2; ks++) {
            const int e = (ks * 32 + kq) ^ swz;
            bf16x8 af[4], bfr[4];
            #pragma unroll
            for (int mt = 0; mt < 4; mt++)
                af[mt] = *(const bf16x8*)&As[(wm + mt * 16 + mrow) * TK + e];
            #pragma unroll
            for (int nt = 0; nt < 4; nt++)
                bfr[nt] = *(const bf16x8*)&Bs[(wn + nt * 16 + mrow) * TK + e];
            #pragma unroll
            for (int mt = 0; mt < 4; mt++)
                #pragma unroll
                for (int nt = 0; nt < 4; nt++)
                    acc[mt][nt] = __builtin_amdgcn_mfma_f32_16x16x32_bf16(
                        af[mt], bfr[nt], acc[mt][nt], 0, 0, 0);
        }
    }

    int seg = bn / 768;                      // 0=q 1=k 2=v 3=kg 4=vg
    int colw_base = bn - seg * 768 + wn;
    float scl = (seg == 0) ? QSC2 : 1.0f;
    // global-row mask (only needed for seg==2: vb read only at global rows)
    unsigned gmask = 0;
    if (seg == 2) {
        #pragma unroll
        for (int mt = 0; mt < 4; mt++)
            #pragma unroll
            for (int rr = 0; rr < 4; rr++)
                gmask |= (unsigned)(is_glb[bm + wm + mt * 16 + row_l + rr] != 0)
                         << (mt * 4 + rr);
    }
    #pragma unroll
    for (int nt = 0; nt < 4; nt++) {
        int col = bn + wn + nt * 16 + col_l;
        int colw = colw_base + nt * 16 + col_l;
        float bs = bias[col];
        #pragma unroll
        for (int mt = 0; mt < 4; mt++) {
            floatx4 v = acc[mt][nt];
            int row0 = bm + wm + mt * 16 + row_l;
            __bf16 t4[4];
            #pragma unroll
            for (int rr = 0; rr < 4; rr++) t4[rr] = (__bf16)((v[rr] + bs) * scl);
            if (seg == 2) {
                #pragma unroll
                for (int rr = 0; rr < 4; rr++)
                    if ((gmask >> (mt * 4 + rr)) & 1)
                        vb[(size_t)(row0 + rr) * 768 + colw] = t4[rr];
            } else if (seg <= 3) {
                __bf16* dst = (seg == 0) ? qb : (seg == 1) ? kb : kgb;
                #pragma unroll
                for (int rr = 0; rr < 4; rr++)
                    dst[(size_t)(row0 + rr) * 768 + colw] = t4[rr];
            }
            if (seg == 2)
                *(uint2*)&vtg[(size_t)colw * SEQ + row0] = *(uint2*)t4;
            if (seg == 4)
                *(uint2*)&vgt[(size_t)colw * SEQ + row0] = *(uint2*)t4;
        }
    }
}

// ========= unified attention: band full-pass (z<2) + gq flash (z>=2) ==========
// l is accumulated via an extra ones-B MFMA (exactly l' = l*alpha + sum(p));
// defer-max (THR=8, exact shift-invariance) skips rescale when max growth <= THR.
__global__ __launch_bounds__(256) void attn_kernel(
    const __bf16* __restrict__ qb, const __bf16* __restrict__ kb,
    const __bf16* __restrict__ vb, const __bf16* __restrict__ vtg,
    const __bf16* __restrict__ qgbb, const __bf16* __restrict__ kgb,
    const __bf16* __restrict__ vgt,
    const int* __restrict__ clss, const int* __restrict__ mask_src,
    const int* __restrict__ is_glb,
    float* __restrict__ OpartG, float* __restrict__ mlpartG,
    __bf16* __restrict__ outb)
{
    __shared__ __align__(16) __bf16 Kt[4096];
    __shared__ __align__(16) __bf16 Vt[4096];
    __shared__ __align__(16) __bf16 Ps[4][32 * PS_LD];
    __shared__ int kvalid[64];
    __shared__ int gpos[64];

    const int hh = blockIdx.y;
    const int t = threadIdx.x, wave = t >> 6, lane = t & 63;
    const int quad = lane >> 4, col_l = lane & 15, row_l = quad * 4;
    const int l3 = lane & 3, l2h = lane >> 2, l7 = lane & 7, l3h = lane >> 3;
    __bf16* PsW = Ps[wave];

    bf16x8 ones8;
    #pragma unroll
    for (int i = 0; i < 8; i++) ones8[i] = (__bf16)1.0f;

    if (blockIdx.z >= 2) {
        // ---------- gq flash: split sp over 32, 4 waves x 16 queries ----------
        const int sp = blockIdx.x * 2 + (blockIdx.z - 2);
        bf16x8 aq[2];
        {
            const __bf16* qp = qgbb + (size_t)(wave * 16 + col_l) * DIM + hh * HDIM;
            aq[0] = *(const bf16x8*)(qp + quad * 8);
            aq[1] = *(const bf16x8*)(qp + 32 + quad * 8);
        }
        floatx4 oacc[4], oaccE;
        #pragma unroll
        for (int i = 0; i < 4; i++) { floatx4 z = {0.f,0.f,0.f,0.f}; oacc[i] = z; }
        { floatx4 z = {0.f,0.f,0.f,0.f}; oaccE = z; }
        float m4[4];
        #pragma unroll
        for (int r = 0; r < 4; r++) m4[r] = -1e30f;

        for (int tt = 0; tt < 2; tt++) {
            int pos0 = sp * 128 + tt * 64;
            __syncthreads();
            if (t < 64) kvalid[t] = (mask_src[pos0 + t] > 0) ? 1 : 0;
            #pragma unroll
            for (int ii = 0; ii < 2; ii++) {
                int gid = wave * 2 + ii;
                int p = gid >> 2, kbase = (gid & 3) * 16;
                async16(kgb + (size_t)(pos0 + kbase + l2h) * DIM + hh * HDIM + p * 32 + l3 * 8,
                        &Kt[p * 2048 + kbase * 32]);
            }
            #pragma unroll
            for (int ii = 0; ii < 2; ii++) {
                int gid = wave * 2 + ii;
                int p = gid >> 2, dbase = (gid & 3) * 16;
                async16(vgt + (size_t)(hh * HDIM + dbase + l2h) * SEQ + pos0 + p * 32 + l3 * 8,
                        &Vt[p * 2048 + dbase * 32]);
            }
            __builtin_amdgcn_s_waitcnt(0x0f70);
            __syncthreads();

            floatx4 s[4];
            #pragma unroll
            for (int nt = 0; nt < 4; nt++) {
                bf16x8 b0 = *(const bf16x8*)&Kt[(nt * 16 + col_l) * 32 + quad * 8];
                bf16x8 b1 = *(const bf16x8*)&Kt[2048 + (nt * 16 + col_l) * 32 + quad * 8];
                floatx4 z = {0.f,0.f,0.f,0.f};
                z = __builtin_amdgcn_mfma_f32_16x16x32_bf16(aq[0], b0, z, 0,0,0);
                z = __builtin_amdgcn_mfma_f32_16x16x32_bf16(aq[1], b1, z, 0,0,0);
                s[nt] = z;
            }
            #pragma unroll
            for (int nt = 0; nt < 4; nt++) {
                int kvv = kvalid[nt * 16 + col_l];
                #pragma unroll
                for (int rr = 0; rr < 4; rr++)
                    if (!kvv) s[nt][rr] = -1e30f;
            }
            float rmx[4]; int grow = 0;
            #pragma unroll
            for (int rr = 0; rr < 4; rr++) {
                float rm = fmaxf(fmaxf(s[0][rr], s[1][rr]), fmaxf(s[2][rr], s[3][rr]));
                rm = fmaxf(rm, __shfl_xor(rm, 1));
                rm = fmaxf(rm, __shfl_xor(rm, 2));
                rm = fmaxf(rm, __shfl_xor(rm, 4));
                rm = fmaxf(rm, __shfl_xor(rm, 8));
                rmx[rr] = rm;
                grow |= (rm > m4[rr] + DEFER_THR) ? 1 : 0;
            }
            if (__any(grow)) {
                #pragma unroll
                for (int rr = 0; rr < 4; rr++) {
                    float mo = m4[rr];
                    float mn = fmaxf(mo, rmx[rr]);
                    float alpha = exp2f(mo - mn);
                    m4[rr] = mn;
                    #pragma unroll
                    for (int nt = 0; nt < 4; nt++) oacc[nt][rr] *= alpha;
                    oaccE[rr] *= alpha;
                }
            }
            #pragma unroll
            for (int rr = 0; rr < 4; rr++) {
                float mn = m4[rr];
                #pragma unroll
                for (int nt = 0; nt < 4; nt++) {
                    float p = exp2f(s[nt][rr] - mn);
                    PsW[(row_l + rr) * PS_LD + nt * 16 + col_l] = (__bf16)p;
                }
            }
            bf16x8 ap0 = *(const bf16x8*)&PsW[col_l * PS_LD + quad * 8];
            bf16x8 ap1 = *(const bf16x8*)&PsW[col_l * PS_LD + 32 + quad * 8];
            oaccE = __builtin_amdgcn_mfma_f32_16x16x32_bf16(ap0, ones8, oaccE, 0,0,0);
            oaccE = __builtin_amdgcn_mfma_f32_16x16x32_bf16(ap1, ones8, oaccE, 0,0,0);
            #pragma unroll
            for (int nt = 0; nt < 4; nt++) {
                bf16x8 b0 = *(const bf16x8*)&Vt[(nt * 16 + col_l) * 32 + quad * 8];
                bf16x8 b1 = *(const bf16x8*)&Vt[2048 + (nt * 16 + col_l) * 32 + quad * 8];
                oacc[nt] = __builtin_amdgcn_mfma_f32_16x16x32_bf16(ap0, b0, oacc[nt], 0,0,0);
                oacc[nt] = __builtin_amdgcn_mfma_f32_16x16x32_bf16(ap1, b1, oacc[nt], 0,0,0);
            }
        }
        size_t base = (size_t)(hh * 32 + sp) * 64;
        #pragma unroll
        for (int nt = 0; nt < 4; nt++)
            #pragma unroll
            for (int rr = 0; rr < 4; rr++)
                OpartG[(base + wave * 16 + row_l + rr) * 64 + nt * 16 + col_l] = oacc[nt][rr];
        if (col_l == 0) {
            #pragma unroll
            for (int rr = 0; rr < 4; rr++) {
                mlpartG[(base + wave * 16 + row_l + rr) * 2]     = m4[rr];
                mlpartG[(base + wave * 16 + row_l + rr) * 2 + 1] = oaccE[rr];
            }
        }
        return;
    }

    // ---------- band + global-key flash: full pass (11 tiles) ----------
    const int n = blockIdx.x, qh = blockIdx.z;
    const int qw = qh * 128 + wave * 32;

    if (t < 64) gpos[t] = clss[t];

    bf16x8 aq[2][2];
    #pragma unroll
    for (int mt = 0; mt < 2; mt++) {
        const __bf16* qp = qb + (size_t)(n * CHK + qw + mt * 16 + col_l) * DIM + hh * HDIM;
        aq[mt][0] = *(const bf16x8*)(qp + quad * 8);
        aq[mt][1] = *(const bf16x8*)(qp + 32 + quad * 8);
    }

    floatx4 oacc[2][4];
    floatx4 oaccE[2];
    #pragma unroll
    for (int i = 0; i < 2; i++) {
        #pragma unroll
        for (int j = 0; j < 4; j++) { floatx4 z = {0.f,0.f,0.f,0.f}; oacc[i][j] = z; }
        floatx4 z = {0.f,0.f,0.f,0.f}; oaccE[i] = z;
    }
    float mrw[8];
    #pragma unroll
    for (int r = 0; r < 8; r++) mrw[r] = -1e30f;

    for (int tt = 0; tt < 11; tt++) {
        __syncthreads();
        int jbase = -1;
        int isglob = (tt == 0);
        if (isglob) {
            if (t < 64) kvalid[t] = (mask_src[gpos[t]] > 0) ? 1 : 0;
            #pragma unroll
            for (int g = 0; g < 2; g++) {
                int gid = wave * 2 + g;
                int p = gid >> 2, kbase = (gid & 3) * 16;
                int pos = gpos[kbase + l2h];
                async16(kb + (size_t)pos * DIM + hh * HDIM + p * 32 + l3 * 8,
                        &Kt[p * 2048 + kbase * 32]);
            }
            __bf16* Vrow = &Ps[0][0];
            #pragma unroll
            for (int g = 0; g < 2; g++) {
                int cg = wave * 2 + g;
                int pos = gpos[cg * 8 + l3h];
                async16(vb + (size_t)pos * DIM + hh * HDIM + l7 * 8,
                        &Vrow[cg * 64 * 8]);
            }
        } else {
            int jt = qh * 2 + tt - 1;
            jbase = jt * 64;
            if (t < 64) {
                int pos = n * CHK + jbase + t - CHK;
                kvalid[t] = (pos >= 0 && pos < SEQ && mask_src[pos] > 0
                             && is_glb[pos] == 0) ? 1 : 0;
            }
            int s0 = n * CHK + jbase - CHK;
            #pragma unroll
            for (int g = 0; g < 2; g++) {
                int gid = wave * 2 + g;
                int p = gid >> 2, kbase = (gid & 3) * 16;
                int pos = s0 + kbase + l2h; pos = min(max(pos, 0), SEQ - 1);
                async16(kb + (size_t)pos * DIM + hh * HDIM + p * 32 + l3 * 8,
                        &Kt[p * 2048 + kbase * 32]);
            }
            #pragma unroll
            for (int g = 0; g < 2; g++) {
                int gid = wave * 2 + g;
                int p = gid >> 2, dbase = (gid & 3) * 16;
                int d = dbase + l2h;
                int s = s0 + p * 32 + l3 * 8; s = min(max(s, 0), SEQ - 8);
                async16(vtg + (size_t)(hh * HDIM + d) * SEQ + s,
                        &Vt[p * 2048 + dbase * 32]);
            }
        }
        __builtin_amdgcn_s_waitcnt(0x0f70);
        __syncthreads();
        if (isglob) {
            const __bf16* Vrow = &Ps[0][0];
            for (int idx = t; idx < 4096; idx += 256) {
                int key = idx >> 6, d = idx & 63;
                Vt[(key >> 5) * 2048 + d * 32 + (key & 31)] = Vrow[idx];
            }
            __syncthreads();
        } else {
            if (jbase + 63 < qw || jbase > qw + 543) continue;
        }

        bf16x8 bkf[4][2];
        #pragma unroll
        for (int nt = 0; nt < 4; nt++) {
            bkf[nt][0] = *(const bf16x8*)&Kt[(nt * 16 + col_l) * 32 + quad * 8];
            bkf[nt][1] = *(const bf16x8*)&Kt[2048 + (nt * 16 + col_l) * 32 + quad * 8];
        }
        int kv[4];
        #pragma unroll
        for (int nt = 0; nt < 4; nt++) kv[nt] = kvalid[nt * 16 + col_l];

        #pragma unroll
        for (int mt = 0; mt < 2; mt++) {
            floatx4 s[4];
            #pragma unroll
            for (int nt = 0; nt < 4; nt++) {
                floatx4 z = {0.f,0.f,0.f,0.f};
                z = __builtin_amdgcn_mfma_f32_16x16x32_bf16(aq[mt][0], bkf[nt][0], z, 0,0,0);
                z = __builtin_amdgcn_mfma_f32_16x16x32_bf16(aq[mt][1], bkf[nt][1], z, 0,0,0);
                s[nt] = z;
            }
            #pragma unroll
            for (int nt = 0; nt < 4; nt++)
                #pragma unroll
                for (int rr = 0; rr < 4; rr++) {
                    int ok = kv[nt];
                    if (!isglob) {
                        int i = qw + mt * 16 + row_l + rr;
                        int rel = jbase + nt * 16 + col_l - i;
                        ok = ok && (rel >= 0) && (rel <= 2 * WINR);
                    }
                    if (!ok) s[nt][rr] = -1e30f;
                }
            float rmx[4]; int grow = 0;
            #pragma unroll
            for (int rr = 0; rr < 4; rr++) {
                float rm = fmaxf(fmaxf(s[0][rr], s[1][rr]), fmaxf(s[2][rr], s[3][rr]));
                rm = fmaxf(rm, __shfl_xor(rm, 1));
                rm = fmaxf(rm, __shfl_xor(rm, 2));
                rm = fmaxf(rm, __shfl_xor(rm, 4));
                rm = fmaxf(rm, __shfl_xor(rm, 8));
                rmx[rr] = rm;
                grow |= (rm > mrw[mt * 4 + rr] + DEFER_THR) ? 1 : 0;
            }
            if (__any(grow)) {
                #pragma unroll
                for (int rr = 0; rr < 4; rr++) {
                    int ri = mt * 4 + rr;
                    float mo = mrw[ri];
                    float mn = fmaxf(mo, rmx[rr]);
                    float alpha = exp2f(mo - mn);
                    mrw[ri] = mn;
                    #pragma unroll
                    for (int nt = 0; nt < 4; nt++) oacc[mt][nt][rr] *= alpha;
                    oaccE[mt][rr] *= alpha;
                }
            }
            #pragma unroll
            for (int rr = 0; rr < 4; rr++) {
                float mn = mrw[mt * 4 + rr];
                #pragma unroll
                for (int nt = 0; nt < 4; nt++) {
                    float p = exp2f(s[nt][rr] - mn);
                    PsW[(mt * 16 + row_l + rr) * PS_LD + nt * 16 + col_l] = (__bf16)p;
                }
            }
        }
        bf16x8 bvf[4][2], ap[2][2];
        #pragma unroll
        for (int nt = 0; nt < 4; nt++) {
            bvf[nt][0] = *(const bf16x8*)&Vt[(nt * 16 + col_l) * 32 + quad * 8];
            bvf[nt][1] = *(const bf16x8*)&Vt[2048 + (nt * 16 + col_l) * 32 + quad * 8];
        }
        #pragma unroll
        for (int mt = 0; mt < 2; mt++) {
            ap[mt][0] = *(const bf16x8*)&PsW[(mt * 16 + col_l) * PS_LD + quad * 8];
            ap[mt][1] = *(const bf16x8*)&PsW[(mt * 16 + col_l) * PS_LD + 32 + quad * 8];
        }
        #pragma unroll
        for (int mt = 0; mt < 2; mt++) {
            oaccE[mt] = __builtin_amdgcn_mfma_f32_16x16x32_bf16(ap[mt][0], ones8, oaccE[mt], 0,0,0);
            oaccE[mt] = __builtin_amdgcn_mfma_f32_16x16x32_bf16(ap[mt][1], ones8, oaccE[mt], 0,0,0);
            #pragma unroll
            for (int nt = 0; nt < 4; nt++) {
                oacc[mt][nt] = __builtin_amdgcn_mfma_f32_16x16x32_bf16(
                    ap[mt][0], bvf[nt][0], oacc[mt][nt], 0,0,0);
                oacc[mt][nt] = __builtin_amdgcn_mfma_f32_16x16x32_bf16(
                    ap[mt][1], bvf[nt][1], oacc[mt][nt], 0,0,0);
            }
        }
    }

    // normalized bf16 write, skipping global rows (gq_finalize owns those)
    #pragma unroll
    for (int mt = 0; mt < 2; mt++) {
        #pragma unroll
        for (int rr = 0; rr < 4; rr++) {
            int srow = n * CHK + qw + mt * 16 + row_l + rr;
            if (is_glb[srow]) continue;
            float inv = 1.0f / oaccE[mt][rr];
            #pragma unroll
            for (int nt = 0; nt < 4; nt++)
                outb[(size_t)srow * DIM + hh * HDIM + nt * 16 + col_l] =
                    (__bf16)(oacc[mt][nt][rr] * inv);
        }
    }
}

// ---------------- gq finalize: 32-way merge for the 64 global rows -------------
__global__ __launch_bounds__(64) void gq_finalize(
    const float* __restrict__ OpartG, const float* __restrict__ mlpartG,
    const int* __restrict__ clss, __bf16* __restrict__ outb)
{
    int r = blockIdx.x, hh = blockIdx.y, d = threadIdx.x;
    float M = -1e30f;
    for (int sp = 0; sp < 32; sp++)
        M = fmaxf(M, mlpartG[(((size_t)hh * 32 + sp) * 64 + r) * 2]);
    float L = 0.f, acc = 0.f;
    for (int sp = 0; sp < 32; sp++) {
        size_t b = ((size_t)hh * 32 + sp) * 64 + r;
        float w = exp2f(mlpartG[b * 2] - M);
        L += mlpartG[b * 2 + 1] * w;
        acc += w * OpartG[b * 64 + d];
    }
    int pos = clss[r];
    outb[(size_t)pos * DIM + hh * HDIM + d] = (__bf16)(acc / L);
}

// ---------------- host launcher ----------------
extern "C" void kernel_launch(void* const* d_in, const int* in_sizes, int n_in,
                              void* d_out, int out_size, void* d_ws, size_t ws_size,
                              hipStream_t stream)
{
    const int* x        = (const int*)d_in[0];
    const int* mask_src = (const int*)d_in[1];
    const int* clss     = (const int*)d_in[2];
    const int* segs     = (const int*)d_in[3];
    const float* word_emb = (const float*)d_in[4];
    const float* pos_emb  = (const float*)d_in[5];
    const float* type_emb = (const float*)d_in[6];
    const float* ln_e_s   = (const float*)d_in[7];
    const float* ln_e_b   = (const float*)d_in[8];
    const float* Wq  = (const float*)d_in[9];
    const float* bq  = (const float*)d_in[10];
    const float* Wk  = (const float*)d_in[11];
    const float* bk  = (const float*)d_in[12];
    const float* Wv  = (const float*)d_in[13];
    const float* bv  = (const float*)d_in[14];
    const float* Wqg = (const float*)d_in[15];
    const float* bqg = (const float*)d_in[16];
    const float* Wkg = (const float*)d_in[17];
    const float* bkg = (const float*)d_in[18];
    const float* Wvg = (const float*)d_in[19];
    const float* bvg = (const float*)d_in[20];
    const float* Wo  = (const float*)d_in[21];
    const float* bo  = (const float*)d_in[22];
    const float* ln1_s = (const float*)d_in[23];
    const float* ln1_b = (const float*)d_in[24];
    const float* Wf1 = (const float*)d_in[25];
    const float* bf1 = (const float*)d_in[26];
    const float* Wf2 = (const float*)d_in[27];
    const float* bf2 = (const float*)d_in[28];
    const float* ln2_s = (const float*)d_in[29];
    const float* ln2_b = (const float*)d_in[30];

    const size_t DD = (size_t)DIM * DIM;
    float* ws = (float*)d_ws;
    float*  h    = ws;
    float*  s4   = ws + SD;
    __bf16* hb   = (__bf16*)(ws + 2 * SD);
    __bf16* b6b  = (__bf16*)(ws + 2 * SD) + SD;
    __bf16* qb   = (__bf16*)(ws + 3 * SD);
    __bf16* kb   = (__bf16*)(ws + 3 * SD) + SD;
    __bf16* vb   = (__bf16*)(ws + 4 * SD);
    __bf16* vtg  = (__bf16*)(ws + 4 * SD) + SD;
    __bf16* kgb  = (__bf16*)(ws + 5 * SD);
    __bf16* vgt  = (__bf16*)(ws + 5 * SD) + SD;
    __bf16* gelu_b = qb;
    float* extra = ws + 6 * SD;
    __bf16* Wbf   = (__bf16*)extra;                     // 30*DD bf16
    float* after_w = extra + 15 * DD;
    float* bqkv   = after_w;                            // 2*3840
    float* OpartG = bqkv + 7680;                        // 12*32*64*64 = 1,572,864
    float* mlpartG= OpartG + 1572864;                   // 49,152
    float* s4b    = mlpartG + 49152;                    // SD (split-K partial)
    __bf16* qgbb  = (__bf16*)(s4b + SD);                // 64*768 bf16
    int*   isglb  = (int*)(qgbb + (size_t)NCLS * DIM);  // SEQ

    embed_ln_kernel<<<SEQ / 4, 256, 0, stream>>>(x, segs, word_emb, pos_emb, type_emb,
                                                 ln_e_s, ln_e_b, h, hb, isglb);
    {
        TArgs ta{};
        ta.p14[0] = Wq;        ta.p14[1] = Wk;        ta.p14[2] = Wv;
        ta.p14[3] = Wkg;       ta.p14[4] = Wvg;
        ta.p14[5] = Wq + DD;   ta.p14[6] = Wk + DD;   ta.p14[7] = Wv + DD;
        ta.p14[8] = Wkg + DD;  ta.p14[9] = Wvg + DD;
        ta.p14[10] = Wo;       ta.p14[11] = Wo + DD;
        ta.p14[12] = Wqg;      ta.p14[13] = Wqg + DD;
        ta.f1[0] = Wf1; ta.f1[1] = Wf1 + (size_t)DIM * FFD;
        ta.f2[0] = Wf2; ta.f2[1] = Wf2 + (size_t)FFD * DIM;
        tpose_setup_kernel<<<17310, 256, 0, stream>>>(ta, Wbf, bq, bk, bv, bkg, bvg,
                                                      bqkv, clss, isglb);
    }

    for (int l = 0; l < NLAYER; l++) {
        const float* bqg_l = bqg + (size_t)l * DIM;
        const float* bo_l  = bo  + (size_t)l * DIM;
        const float* bf1_l = bf1 + (size_t)l * FFD;
        const float* bf2_l = bf2 + (size_t)l * DIM;

        // fused 5-way projection + qg gather tiles (y>=30)
        mfma_gemm_proj<<<dim3(SEQ / 128, 36), 256, 0, stream>>>(
            hb, Wbf + (size_t)l * 5 * DD, bqkv + l * 3840,
            qb, kb, vb, vtg, kgb, vgt, DIM,
            Wbf + 12 * DD + (size_t)l * DD, bqg_l, clss, qgbb, isglb);
        // unified band (full-pass, direct bf16 out) + gq attention
        attn_kernel<<<dim3(NCHK, NH, 4), 256, 0, stream>>>(
            qb, kb, vb, vtg, qgbb, kgb, vgt, clss, mask_src, isglb,
            OpartG, mlpartG, b6b);
        gq_finalize<<<dim3(NCLS, NH), 64, 0, stream>>>(OpartG, mlpartG, clss, b6b);
        // output projection (split-K=2) + LN1
        mfma_gemm_t<128, 64><<<dim3(SEQ / 128, DIM / 64, 2), 256, 0, stream>>>(
            b6b, Wbf + 10 * DD + (size_t)l * DD, bo_l, s4, s4b, nullptr,
            SEQ, DIM, DIM, 1.0f, 0);
        add_ln_kernel<<<SEQ / 4, 256, 0, stream>>>(h, s4, s4b, ln1_s + (size_t)l * DIM,
                                                   ln1_b + (size_t)l * DIM, h, hb);
        // FFN
        mfma_gemm_t<128, 128><<<dim3(SEQ / 128, FFD / 128, 1), 256, 0, stream>>>(
            hb, Wbf + 14 * DD + (size_t)l * 4 * DD, bf1_l, nullptr, nullptr, gelu_b,
            SEQ, FFD, DIM, 1.0f, 1);
        mfma_gemm_t<128, 64><<<dim3(SEQ / 128, DIM / 64, 2), 256, 0, stream>>>(
            gelu_b, Wbf + 22 * DD + (size_t)l * 4 * DD, bf2_l, s4, s4b, nullptr,
            SEQ, DIM, FFD, 1.0f, 0);
        add_ln_kernel<<<SEQ / 4, 256, 0, stream>>>(h, s4, s4b, ln2_s + (size_t)l * DIM,
                                                   ln2_b + (size_t)l * DIM,
                                                   (l == NLAYER - 1) ? (float*)d_out : h, hb);
    }
}